// Round 1
// baseline (4211.607 us; speedup 1.0000x reference)
//
#include <hip/hip_runtime.h>
#include <hip/hip_bf16.h>

#define NN 50000
#define EE 640000
#define NEG 0.2f

// ---------------- transpose all weight matrices into ws ----------------
// layout: [embV 64x128][embC 64x128][sv0][sv1][sc0][sc1][cpl][cpr][cnl][cnr] (each 128x128)
__global__ void transpose_all(const float* __restrict__ wev, const float* __restrict__ wec,
                              const float* __restrict__ svW, const float* __restrict__ scW,
                              const float* __restrict__ cpl, const float* __restrict__ cpr,
                              const float* __restrict__ cnl, const float* __restrict__ cnr,
                              float* __restrict__ out)
{
    int i = blockIdx.x * 256 + threadIdx.x;
    if (i < 8192)  { out[i] = wev[(i & 127) * 64 + (i >> 7)]; return; }
    if (i < 16384) { int j = i - 8192; out[i] = wec[(j & 127) * 64 + (j >> 7)]; return; }
    int t = i - 16384;
    int m = t >> 14, j = t & 16383;
    const float* src;
    switch (m) {
        case 0:  src = svW;         break;
        case 1:  src = svW + 16384; break;
        case 2:  src = scW;         break;
        case 3:  src = scW + 16384; break;
        case 4:  src = cpl;         break;
        case 5:  src = cpr;         break;
        case 6:  src = cnl;         break;
        default: src = cnr;         break;
    }
    out[i] = src[(j & 127) * 128 + (j >> 7)];
}

// ---------------- embedding GEMM + LayerNorm ----------------
// x:[NN,64], Wt:[64,128]. Writes F[n][c] = xv + biassum[c]  (residual accumulator seed)
//                            C[n][c] = LN(xv)*g + b
__global__ void embed_ln(const float* __restrict__ x, const float* __restrict__ Wt,
                         const float* __restrict__ g, const float* __restrict__ b,
                         const float* __restrict__ pw, const float* __restrict__ sb,
                         float* __restrict__ F, float* __restrict__ C)
{
    __shared__ float lx[8][64];
    __shared__ float red[2][8][2];
    int c = threadIdx.x;
    int n0 = blockIdx.x * 8;
    for (int t = c; t < 8 * 64; t += 128) {
        lx[t >> 6][t & 63] = x[(size_t)(n0 + (t >> 6)) * 64 + (t & 63)];
    }
    __syncthreads();
    float acc[8];
#pragma unroll
    for (int m = 0; m < 8; m++) acc[m] = 0.f;
    for (int k = 0; k < 64; k++) {
        float w = Wt[k * 128 + c];
#pragma unroll
        for (int m = 0; m < 8; m++) acc[m] += lx[m][k] * w;
    }
    int lane = c & 63, wv = c >> 6;
#pragma unroll
    for (int m = 0; m < 8; m++) {
        float s1 = acc[m], s2 = acc[m] * acc[m];
        for (int off = 32; off; off >>= 1) { s1 += __shfl_xor(s1, off); s2 += __shfl_xor(s2, off); }
        if (lane == 0) { red[wv][m][0] = s1; red[wv][m][1] = s2; }
    }
    __syncthreads();
    float biassum = pw[0] * sb[c] + pw[1] * sb[128 + c];
    float gg = g[c], bb = b[c];
#pragma unroll
    for (int m = 0; m < 8; m++) {
        float s1 = red[0][m][0] + red[1][m][0];
        float s2 = red[0][m][1] + red[1][m][1];
        float mu  = s1 * (1.f / 128.f);
        float var = s2 * (1.f / 128.f) - mu * mu;
        float inv = rsqrtf(var + 1e-5f);
        float v = acc[m];
        size_t idx = (size_t)(n0 + m) * 128 + c;
        F[idx] = v + biassum;
        C[idx] = (v - mu) * inv * gg + bb;
    }
}

// ---------------- generic 128x128 projection: out = in @ W^T (Wt pre-transposed) ----------------
__global__ void gemm128(const float* __restrict__ in, const float* __restrict__ Wt,
                        float* __restrict__ out)
{
    __shared__ float lx[8][128];
    int c = threadIdx.x;
    int n0 = blockIdx.x * 8;
    for (int t = c; t < 8 * 128; t += 128) {
        lx[t >> 7][t & 127] = in[(size_t)n0 * 128 + t];
    }
    __syncthreads();
    float acc[8];
#pragma unroll
    for (int m = 0; m < 8; m++) acc[m] = 0.f;
    for (int k = 0; k < 128; k++) {
        float w = Wt[k * 128 + c];
#pragma unroll
        for (int m = 0; m < 8; m++) acc[m] += lx[m][k] * w;
    }
#pragma unroll
    for (int m = 0; m < 8; m++) out[(size_t)(n0 + m) * 128 + c] = acc[m];
}

// ---------------- per-node attention dots: dl[n][h]=x[n]·attL[:,h], dr likewise ----------------
__global__ void node_dots(const float* __restrict__ x, const float* __restrict__ attL,
                          const float* __restrict__ attR,
                          float* __restrict__ dl, float* __restrict__ dr)
{
    int wv = threadIdx.x >> 6, lane = threadIdx.x & 63;
    int n = blockIdx.x * 4 + wv;
    if (n >= NN) return;
    float x0 = x[(size_t)n * 128 + lane];
    float x1 = x[(size_t)n * 128 + 64 + lane];
    float pl[4], pr[4];
#pragma unroll
    for (int h = 0; h < 4; h++) {
        pl[h] = x0 * attL[lane * 4 + h] + x1 * attL[(64 + lane) * 4 + h];
        pr[h] = x0 * attR[lane * 4 + h] + x1 * attR[(64 + lane) * 4 + h];
    }
    for (int off = 32; off; off >>= 1) {
#pragma unroll
        for (int h = 0; h < 4; h++) { pl[h] += __shfl_xor(pl[h], off); pr[h] += __shfl_xor(pr[h], off); }
    }
    if (lane == 0) {
#pragma unroll
        for (int h = 0; h < 4; h++) { dl[n * 4 + h] = pl[h]; dr[n * 4 + h] = pr[h]; }
    }
}

// ---------------- zero a buffer ----------------
__global__ void zero_buf(float* __restrict__ p, int n)
{
    int i = blockIdx.x * 256 + threadIdx.x;
    if (i < n) p[i] = 0.f;
}

// ---------------- init output with biases ----------------
__global__ void init_out(const float* __restrict__ b0, const float* __restrict__ b1,
                         float* __restrict__ out)
{
    int i = blockIdx.x * 256 + threadIdx.x;
    if (i < 2 * NN * 128) out[i] = b0[i & 127] + b1[i & 127];
}

// ---------------- denominator accumulation ----------------
// score[h] = leaky(a_dst[dst][h] + a_src[src][h]); den[dst][h] += exp(score)
__global__ void edge_den(const int* __restrict__ srcI, const int* __restrict__ dstI,
                         int nE, int nLoop,
                         const float* __restrict__ a_dst, const float* __restrict__ a_src,
                         float* __restrict__ den)
{
    int e = blockIdx.x * 256 + threadIdx.x;
    if (e >= nE + nLoop) return;
    int s, d;
    if (e < nE) { s = srcI[e]; d = dstI[e]; } else { s = d = e - nE; }
    float4 ad = *(const float4*)(a_dst + (size_t)d * 4);
    float4 as = *(const float4*)(a_src + (size_t)s * 4);
    float sc[4] = {ad.x + as.x, ad.y + as.y, ad.z + as.z, ad.w + as.w};
#pragma unroll
    for (int h = 0; h < 4; h++) {
        float v = sc[h];
        v = v > 0.f ? v : NEG * v;
        atomicAdd(&den[(size_t)d * 4 + h], __expf(v));
    }
}

// ---------------- per-edge mean-head alpha (scaled) ----------------
__global__ void edge_wbar(const int* __restrict__ srcI, const int* __restrict__ dstI,
                          int nE, int nLoop,
                          const float* __restrict__ a_dst, const float* __restrict__ a_src,
                          const float* __restrict__ den,
                          const float* __restrict__ pw, int pwi,
                          float* __restrict__ wbar)
{
    int e = blockIdx.x * 256 + threadIdx.x;
    if (e >= nE + nLoop) return;
    int s, d;
    if (e < nE) { s = srcI[e]; d = dstI[e]; } else { s = d = e - nE; }
    float4 ad = *(const float4*)(a_dst + (size_t)d * 4);
    float4 as = *(const float4*)(a_src + (size_t)s * 4);
    float4 dn = *(const float4*)(den + (size_t)d * 4);
    float sc[4] = {ad.x + as.x, ad.y + as.y, ad.z + as.z, ad.w + as.w};
    float dnv[4] = {dn.x, dn.y, dn.z, dn.w};
    float w = 0.f;
#pragma unroll
    for (int h = 0; h < 4; h++) {
        float v = sc[h];
        v = v > 0.f ? v : NEG * v;
        w += __expf(v) / (dnv[h] + 1e-16f);
    }
    float scale = 0.25f * (pw ? pw[pwi] : 1.0f);
    wbar[e] = w * scale;
}

// ---------------- weighted scatter-add: out[dst] += wbar[e] * feats[src] ----------------
__global__ void edge_agg(const int* __restrict__ srcI, const int* __restrict__ dstI,
                         int nE, int nLoop,
                         const float* __restrict__ wbar, const float* __restrict__ feats,
                         float* __restrict__ out)
{
    int half = threadIdx.x >> 7;
    int c = threadIdx.x & 127;
    int e = blockIdx.x * 2 + half;
    if (e >= nE + nLoop) return;
    int s, d;
    if (e < nE) { s = srcI[e]; d = dstI[e]; } else { s = d = e - nE; }
    float w = wbar[e];
    atomicAdd(&out[(size_t)d * 128 + c], w * feats[(size_t)s * 128 + c]);
}

extern "C" void kernel_launch(void* const* d_in, const int* in_sizes, int n_in,
                              void* d_out, int out_size, void* d_ws, size_t ws_size,
                              hipStream_t stream)
{
    const float* x_var   = (const float*)d_in[0];
    const float* x_cls   = (const float*)d_in[1];
    const int*   mp_var  = (const int*)d_in[2];
    const int*   mp_cls  = (const int*)d_in[3];
    const int*   adj_pos = (const int*)d_in[4];
    const int*   adj_neg = (const int*)d_in[5];
    const float* W_var_emb = (const float*)d_in[6];
    const float* W_cls_emb = (const float*)d_in[7];
    const float* ln_var_g = (const float*)d_in[8];
    const float* ln_var_b = (const float*)d_in[9];
    const float* ln_cls_g = (const float*)d_in[10];
    const float* ln_cls_b = (const float*)d_in[11];
    const float* var_pw = (const float*)d_in[12];
    const float* cls_pw = (const float*)d_in[13];
    const float* sv_W  = (const float*)d_in[14];
    const float* sv_al = (const float*)d_in[15];
    const float* sv_ar = (const float*)d_in[16];
    const float* sv_b  = (const float*)d_in[17];
    const float* sc_W  = (const float*)d_in[18];
    const float* sc_al = (const float*)d_in[19];
    const float* sc_ar = (const float*)d_in[20];
    const float* sc_b  = (const float*)d_in[21];
    const float* cp_Wl = (const float*)d_in[22];
    const float* cp_Wr = (const float*)d_in[23];
    const float* cp_al = (const float*)d_in[24];
    const float* cp_ar = (const float*)d_in[25];
    const float* cp_b  = (const float*)d_in[26];
    const float* cn_Wl = (const float*)d_in[27];
    const float* cn_Wr = (const float*)d_in[28];
    const float* cn_al = (const float*)d_in[29];
    const float* cn_ar = (const float*)d_in[30];
    const float* cn_b  = (const float*)d_in[31];

    float* out0 = (float*)d_out;
    float* out1 = out0 + (size_t)NN * 128;

    float* ws = (float*)d_ws;
    size_t off = 0;
    auto alloc = [&](size_t n) { float* p = ws + off; off += n; return p; };
    float* Wt   = alloc(147456);            // transposed weights
    float* F    = alloc((size_t)NN * 128);  // var residual accumulator -> xv2
    float* G    = alloc((size_t)NN * 128);  // cls residual accumulator -> xc2
    float* C    = alloc((size_t)NN * 128);  // hv, later cross xl
    float* D    = alloc((size_t)NN * 128);  // hc, later cross xr
    float* XL   = alloc((size_t)NN * 128);  // self-attn projection scratch
    float* dl   = alloc(NN * 4);
    float* dr   = alloc(NN * 4);
    float* dl2  = alloc(NN * 4);
    float* dr2  = alloc(NN * 4);
    float* den  = alloc(NN * 4);
    float* den2 = alloc(NN * 4);
    float* wb   = alloc(EE + NN);

    const float* WtEv  = Wt;
    const float* WtEc  = Wt + 8192;
    const float* WtSv0 = Wt + 16384;
    const float* WtSv1 = WtSv0 + 16384;
    const float* WtSc0 = WtSv1 + 16384;
    const float* WtSc1 = WtSc0 + 16384;
    const float* WtCpl = WtSc1 + 16384;
    const float* WtCpr = WtCpl + 16384;
    const float* WtCnl = WtCpr + 16384;
    const float* WtCnr = WtCnl + 16384;

    transpose_all<<<576, 256, 0, stream>>>(W_var_emb, W_cls_emb, sv_W, sc_W,
                                           cp_Wl, cp_Wr, cn_Wl, cn_Wr, Wt);
    embed_ln<<<NN / 8, 128, 0, stream>>>(x_var, WtEv, ln_var_g, ln_var_b, var_pw, sv_b, F, C);
    embed_ln<<<NN / 8, 128, 0, stream>>>(x_cls, WtEc, ln_cls_g, ln_cls_b, cls_pw, sc_b, G, D);
    init_out<<<(2 * NN * 128 + 255) / 256, 256, 0, stream>>>(cp_b, cn_b, out0);

    const int ETOT = EE + NN;
    const int edBlocks  = (ETOT + 255) / 256;
    const int aggBlocks = (ETOT + 1) / 2;

    // ---- self attention (pre-norm, weighted metapath sum, residual into F/G) ----
    for (int side = 0; side < 2; ++side) {
        const float* h    = side ? D : C;
        float*       acc  = side ? G : F;
        const int*   mp   = side ? mp_cls : mp_var;
        const float* attl = side ? sc_al : sv_al;
        const float* attr = side ? sc_ar : sv_ar;
        const float* pw   = side ? cls_pw : var_pw;
        const float* Wts[2] = { side ? WtSc0 : WtSv0, side ? WtSc1 : WtSv1 };
        for (int p = 0; p < 2; ++p) {
            const int* srcI = mp + (size_t)p * 2 * EE;      // adj[0]
            const int* dstI = srcI + EE;                    // adj[1]
            gemm128<<<NN / 8, 128, 0, stream>>>(h, Wts[p], XL);
            node_dots<<<NN / 4, 256, 0, stream>>>(XL, attl + p * 512, attr + p * 512, dl, dr);
            zero_buf<<<(NN * 4 + 255) / 256, 256, 0, stream>>>(den, NN * 4);
            edge_den<<<edBlocks, 256, 0, stream>>>(srcI, dstI, EE, NN, dl, dr, den);
            edge_wbar<<<edBlocks, 256, 0, stream>>>(srcI, dstI, EE, NN, dl, dr, den, pw, p, wb);
            edge_agg<<<aggBlocks, 256, 0, stream>>>(srcI, dstI, EE, NN, wb, XL, acc);
        }
    }

    // ---- cross attention (pos/neg), accumulate into d_out ----
    const int cBlocks = (EE + 255) / 256;
    const int cAgg    = EE / 2;
    for (int sign = 0; sign < 2; ++sign) {
        const int* adj  = sign ? adj_neg : adj_pos;
        const int* cI   = adj;            // clause indices (adj[0])
        const int* vI   = adj + EE;       // variable indices (adj[1])
        const float* Wl   = sign ? WtCnl : WtCpl;
        const float* Wr   = sign ? WtCnr : WtCpr;
        const float* attl = sign ? cn_al : cp_al;
        const float* attr = sign ? cn_ar : cp_ar;
        gemm128<<<NN / 8, 128, 0, stream>>>(F, Wl, C);   // xl (var side)
        gemm128<<<NN / 8, 128, 0, stream>>>(G, Wr, D);   // xr (cls side)
        node_dots<<<NN / 4, 256, 0, stream>>>(C, attl, attr, dl, dr);    // dl=al, dr=ar_
        node_dots<<<NN / 4, 256, 0, stream>>>(D, attl, attr, dl2, dr2);  // dl2=al_, dr2=ar
        // var direction: score = al[v] + ar[c], softmax over v, out0[v] += alpha * xr[c]
        zero_buf<<<(NN * 4 + 255) / 256, 256, 0, stream>>>(den, NN * 4);
        edge_den<<<cBlocks, 256, 0, stream>>>(cI, vI, EE, 0, dl, dr2, den);
        edge_wbar<<<cBlocks, 256, 0, stream>>>(cI, vI, EE, 0, dl, dr2, den, nullptr, 0, wb);
        edge_agg<<<cAgg, 256, 0, stream>>>(cI, vI, EE, 0, wb, D, out0);
        // cls direction: score_ = ar_[v] + al_[c], softmax over c, out1[c] += alpha_ * xl[v]
        zero_buf<<<(NN * 4 + 255) / 256, 256, 0, stream>>>(den2, NN * 4);
        edge_den<<<cBlocks, 256, 0, stream>>>(vI, cI, EE, 0, dl2, dr, den2);
        edge_wbar<<<cBlocks, 256, 0, stream>>>(vI, cI, EE, 0, dl2, dr, den2, nullptr, 0, wb);
        edge_agg<<<cAgg, 256, 0, stream>>>(vI, cI, EE, 0, wb, C, out1);
    }
}

// Round 2
// 2231.741 us; speedup vs baseline: 1.8871x; 1.8871x over previous
//
#include <hip/hip_runtime.h>
#include <hip/hip_bf16.h>

#define NN 50000
#define EE 640000
#define NEG 0.2f
#define CAP 128          // per-segment LDS cache; degree ~ Poisson(12.8), P(k>128) ~ 0

// ---------------- transpose all weight matrices into ws ----------------
__global__ void transpose_all(const float* __restrict__ wev, const float* __restrict__ wec,
                              const float* __restrict__ svW, const float* __restrict__ scW,
                              const float* __restrict__ cpl, const float* __restrict__ cpr,
                              const float* __restrict__ cnl, const float* __restrict__ cnr,
                              float* __restrict__ out)
{
    int i = blockIdx.x * 256 + threadIdx.x;
    if (i < 8192)  { out[i] = wev[(i & 127) * 64 + (i >> 7)]; return; }
    if (i < 16384) { int j = i - 8192; out[i] = wec[(j & 127) * 64 + (j >> 7)]; return; }
    int t = i - 16384;
    int m = t >> 14, j = t & 16383;
    const float* src;
    switch (m) {
        case 0:  src = svW;         break;
        case 1:  src = svW + 16384; break;
        case 2:  src = scW;         break;
        case 3:  src = scW + 16384; break;
        case 4:  src = cpl;         break;
        case 5:  src = cpr;         break;
        case 6:  src = cnl;         break;
        default: src = cnr;         break;
    }
    out[i] = src[(j & 127) * 128 + (j >> 7)];
}

// ---------------- embedding GEMM + LayerNorm ----------------
__global__ void embed_ln(const float* __restrict__ x, const float* __restrict__ Wt,
                         const float* __restrict__ g, const float* __restrict__ b,
                         const float* __restrict__ pw, const float* __restrict__ sb,
                         float* __restrict__ F, float* __restrict__ C)
{
    __shared__ float lx[8][64];
    __shared__ float red[2][8][2];
    int c = threadIdx.x;
    int n0 = blockIdx.x * 8;
    for (int t = c; t < 8 * 64; t += 128) {
        lx[t >> 6][t & 63] = x[(size_t)(n0 + (t >> 6)) * 64 + (t & 63)];
    }
    __syncthreads();
    float acc[8];
#pragma unroll
    for (int m = 0; m < 8; m++) acc[m] = 0.f;
    for (int k = 0; k < 64; k++) {
        float w = Wt[k * 128 + c];
#pragma unroll
        for (int m = 0; m < 8; m++) acc[m] += lx[m][k] * w;
    }
    int lane = c & 63, wv = c >> 6;
#pragma unroll
    for (int m = 0; m < 8; m++) {
        float s1 = acc[m], s2 = acc[m] * acc[m];
        for (int off = 32; off; off >>= 1) { s1 += __shfl_xor(s1, off); s2 += __shfl_xor(s2, off); }
        if (lane == 0) { red[wv][m][0] = s1; red[wv][m][1] = s2; }
    }
    __syncthreads();
    float biassum = pw[0] * sb[c] + pw[1] * sb[128 + c];
    float gg = g[c], bb = b[c];
#pragma unroll
    for (int m = 0; m < 8; m++) {
        float s1 = red[0][m][0] + red[1][m][0];
        float s2 = red[0][m][1] + red[1][m][1];
        float mu  = s1 * (1.f / 128.f);
        float var = s2 * (1.f / 128.f) - mu * mu;
        float inv = rsqrtf(var + 1e-5f);
        float v = acc[m];
        size_t idx = (size_t)(n0 + m) * 128 + c;
        F[idx] = v + biassum;
        C[idx] = (v - mu) * inv * gg + bb;
    }
}

// ---------------- 128x128 projection ----------------
__global__ void gemm128(const float* __restrict__ in, const float* __restrict__ Wt,
                        float* __restrict__ out)
{
    __shared__ float lx[8][128];
    int c = threadIdx.x;
    int n0 = blockIdx.x * 8;
    for (int t = c; t < 8 * 128; t += 128) {
        lx[t >> 7][t & 127] = in[(size_t)n0 * 128 + t];
    }
    __syncthreads();
    float acc[8];
#pragma unroll
    for (int m = 0; m < 8; m++) acc[m] = 0.f;
    for (int k = 0; k < 128; k++) {
        float w = Wt[k * 128 + c];
#pragma unroll
        for (int m = 0; m < 8; m++) acc[m] += lx[m][k] * w;
    }
#pragma unroll
    for (int m = 0; m < 8; m++) out[(size_t)(n0 + m) * 128 + c] = acc[m];
}

// ---------------- per-node attention dots ----------------
__global__ void node_dots(const float* __restrict__ x, const float* __restrict__ attL,
                          const float* __restrict__ attR,
                          float* __restrict__ dl, float* __restrict__ dr)
{
    int wv = threadIdx.x >> 6, lane = threadIdx.x & 63;
    int n = blockIdx.x * 4 + wv;
    if (n >= NN) return;
    float x0 = x[(size_t)n * 128 + lane];
    float x1 = x[(size_t)n * 128 + 64 + lane];
    float pl[4], pr[4];
#pragma unroll
    for (int h = 0; h < 4; h++) {
        pl[h] = x0 * attL[lane * 4 + h] + x1 * attL[(64 + lane) * 4 + h];
        pr[h] = x0 * attR[lane * 4 + h] + x1 * attR[(64 + lane) * 4 + h];
    }
    for (int off = 32; off; off >>= 1) {
#pragma unroll
        for (int h = 0; h < 4; h++) { pl[h] += __shfl_xor(pl[h], off); pr[h] += __shfl_xor(pr[h], off); }
    }
    if (lane == 0) {
#pragma unroll
        for (int h = 0; h < 4; h++) { dl[n * 4 + h] = pl[h]; dr[n * 4 + h] = pr[h]; }
    }
}

// ---------------- init output with biases ----------------
__global__ void init_out(const float* __restrict__ b0, const float* __restrict__ b1,
                         float* __restrict__ out)
{
    int i = blockIdx.x * 256 + threadIdx.x;
    if (i < 2 * NN * 128) out[i] = b0[i & 127] + b1[i & 127];
}

// ---------------- counting-sort pieces ----------------
__global__ void zero_int(int* __restrict__ p, int n)
{
    int i = blockIdx.x * 256 + threadIdx.x;
    if (i < n) p[i] = 0;
}

__global__ void hist_k(const int* __restrict__ dstI, int* __restrict__ counts)
{
    int e = blockIdx.x * 256 + threadIdx.x;
    if (e < EE) atomicAdd(&counts[dstI[e]], 1);
}

__global__ void scan_part(const int* __restrict__ counts, int* __restrict__ blockSums)
{
    __shared__ int red[4];
    int t = threadIdx.x;
    int i = blockIdx.x * 256 + t;
    int v = (i < NN) ? counts[i] : 0;
    for (int off = 32; off; off >>= 1) v += __shfl_xor(v, off);
    if ((t & 63) == 0) red[t >> 6] = v;
    __syncthreads();
    if (t == 0) blockSums[blockIdx.x] = red[0] + red[1] + red[2] + red[3];
}

__global__ void scan_tops(int* __restrict__ blockSums, int nb)
{
    if (threadIdx.x == 0 && blockIdx.x == 0) {
        int acc = 0;
        for (int i = 0; i < nb; i++) { int t = blockSums[i]; blockSums[i] = acc; acc += t; }
    }
}

__global__ void scan_final(const int* __restrict__ counts, const int* __restrict__ blockSums,
                           int* __restrict__ starts, int* __restrict__ cursor)
{
    __shared__ int sh[256];
    int t = threadIdx.x;
    int i = blockIdx.x * 256 + t;
    int v = (i < NN) ? counts[i] : 0;
    sh[t] = v;
    __syncthreads();
    for (int off = 1; off < 256; off <<= 1) {
        int x = (t >= off) ? sh[t - off] : 0;
        __syncthreads();
        sh[t] += x;
        __syncthreads();
    }
    int excl = sh[t] - v + blockSums[blockIdx.x];
    if (i < NN) { starts[i] = excl; cursor[i] = excl; }
}

__global__ void scatter_k(const int* __restrict__ srcI, const int* __restrict__ dstI,
                          int* __restrict__ cursor, int* __restrict__ sortedSrc)
{
    int e = blockIdx.x * 256 + threadIdx.x;
    if (e >= EE) return;
    int d = dstI[e];
    int pos = atomicAdd(&cursor[d], 1);
    sortedSrc[pos] = srcI[e];
}

// ---------------- fused segment softmax + aggregation ----------------
// block = 128 threads, one dst node per block. No atomics; acc[d] += sum_e wbar_e * feats[src_e].
__global__ __launch_bounds__(128) void agg_sorted(
    const int* __restrict__ starts, const int* __restrict__ counts,
    const int* __restrict__ sortedSrc,
    const float* __restrict__ a_dst, const float* __restrict__ a_src,
    const float* __restrict__ feats,
    const float* __restrict__ pw, int pwi, int hasLoop,
    float* __restrict__ acc)
{
    __shared__ float4 exSh[CAP];
    __shared__ int    sSh[CAP];
    __shared__ float  wSh[CAP];
    __shared__ float  red[2][4];
    __shared__ float  denSh[4];

    int d = blockIdx.x;
    int t = threadIdx.x;
    int base = starts[d];
    int k = counts[d];
    int kTot = k + hasLoop;

    float4 ad = *(const float4*)(a_dst + (size_t)d * 4);
    float p0 = 0.f, p1 = 0.f, p2 = 0.f, p3 = 0.f;
    for (int i = t; i < kTot; i += 128) {
        int s = (i < k) ? sortedSrc[base + i] : d;
        float4 as = *(const float4*)(a_src + (size_t)s * 4);
        float v0 = ad.x + as.x, v1 = ad.y + as.y, v2 = ad.z + as.z, v3 = ad.w + as.w;
        v0 = v0 > 0.f ? v0 : NEG * v0;
        v1 = v1 > 0.f ? v1 : NEG * v1;
        v2 = v2 > 0.f ? v2 : NEG * v2;
        v3 = v3 > 0.f ? v3 : NEG * v3;
        float e0 = __expf(v0), e1 = __expf(v1), e2 = __expf(v2), e3 = __expf(v3);
        if (i < CAP) { exSh[i] = make_float4(e0, e1, e2, e3); sSh[i] = s; }
        p0 += e0; p1 += e1; p2 += e2; p3 += e3;
    }
    for (int off = 32; off; off >>= 1) {
        p0 += __shfl_xor(p0, off); p1 += __shfl_xor(p1, off);
        p2 += __shfl_xor(p2, off); p3 += __shfl_xor(p3, off);
    }
    int lane = t & 63, wv = t >> 6;
    if (lane == 0) { red[wv][0] = p0; red[wv][1] = p1; red[wv][2] = p2; red[wv][3] = p3; }
    __syncthreads();
    if (t < 4) denSh[t] = red[0][t] + red[1][t];
    __syncthreads();

    float scale = 0.25f * (pw ? pw[pwi] : 1.0f);
    float d0 = denSh[0] + 1e-16f, d1 = denSh[1] + 1e-16f;
    float d2 = denSh[2] + 1e-16f, d3 = denSh[3] + 1e-16f;
    if (t < CAP && t < kTot) {
        float4 ex = exSh[t];
        wSh[t] = scale * (ex.x / d0 + ex.y / d1 + ex.z / d2 + ex.w / d3);
    }
    __syncthreads();

    float accv = acc[(size_t)d * 128 + t];
    for (int j = 0; j < kTot; j++) {
        float w; int s;
        if (j < CAP) { w = wSh[j]; s = sSh[j]; }
        else {  // astronomically rare fallback (degree > 128)
            s = (j < k) ? sortedSrc[base + j] : d;
            float4 as = *(const float4*)(a_src + (size_t)s * 4);
            float v0 = ad.x + as.x, v1 = ad.y + as.y, v2 = ad.z + as.z, v3 = ad.w + as.w;
            v0 = v0 > 0.f ? v0 : NEG * v0;
            v1 = v1 > 0.f ? v1 : NEG * v1;
            v2 = v2 > 0.f ? v2 : NEG * v2;
            v3 = v3 > 0.f ? v3 : NEG * v3;
            w = scale * (__expf(v0) / d0 + __expf(v1) / d1 + __expf(v2) / d2 + __expf(v3) / d3);
        }
        accv += w * feats[(size_t)s * 128 + t];
    }
    acc[(size_t)d * 128 + t] = accv;
}

extern "C" void kernel_launch(void* const* d_in, const int* in_sizes, int n_in,
                              void* d_out, int out_size, void* d_ws, size_t ws_size,
                              hipStream_t stream)
{
    const float* x_var   = (const float*)d_in[0];
    const float* x_cls   = (const float*)d_in[1];
    const int*   mp_var  = (const int*)d_in[2];
    const int*   mp_cls  = (const int*)d_in[3];
    const int*   adj_pos = (const int*)d_in[4];
    const int*   adj_neg = (const int*)d_in[5];
    const float* W_var_emb = (const float*)d_in[6];
    const float* W_cls_emb = (const float*)d_in[7];
    const float* ln_var_g = (const float*)d_in[8];
    const float* ln_var_b = (const float*)d_in[9];
    const float* ln_cls_g = (const float*)d_in[10];
    const float* ln_cls_b = (const float*)d_in[11];
    const float* var_pw = (const float*)d_in[12];
    const float* cls_pw = (const float*)d_in[13];
    const float* sv_W  = (const float*)d_in[14];
    const float* sv_al = (const float*)d_in[15];
    const float* sv_ar = (const float*)d_in[16];
    const float* sv_b  = (const float*)d_in[17];
    const float* sc_W  = (const float*)d_in[18];
    const float* sc_al = (const float*)d_in[19];
    const float* sc_ar = (const float*)d_in[20];
    const float* sc_b  = (const float*)d_in[21];
    const float* cp_Wl = (const float*)d_in[22];
    const float* cp_Wr = (const float*)d_in[23];
    const float* cp_al = (const float*)d_in[24];
    const float* cp_ar = (const float*)d_in[25];
    const float* cp_b  = (const float*)d_in[26];
    const float* cn_Wl = (const float*)d_in[27];
    const float* cn_Wr = (const float*)d_in[28];
    const float* cn_al = (const float*)d_in[29];
    const float* cn_ar = (const float*)d_in[30];
    const float* cn_b  = (const float*)d_in[31];

    float* out0 = (float*)d_out;
    float* out1 = out0 + (size_t)NN * 128;

    float* ws = (float*)d_ws;
    size_t off = 0;
    auto alloc = [&](size_t n) { float* p = ws + off; off += n; return p; };
    float* Wt   = alloc(147456);
    float* F    = alloc((size_t)NN * 128);
    float* G    = alloc((size_t)NN * 128);
    float* C    = alloc((size_t)NN * 128);
    float* D    = alloc((size_t)NN * 128);
    float* XL   = alloc((size_t)NN * 128);
    float* dl   = alloc(NN * 4);
    float* dr   = alloc(NN * 4);
    float* dl2  = alloc(NN * 4);
    float* dr2  = alloc(NN * 4);
    int* counts    = (int*)alloc(NN);
    int* starts    = (int*)alloc(NN);
    int* cursor    = (int*)alloc(NN);
    int* blockSums = (int*)alloc(256);
    int* sortedSrc = (int*)alloc(EE);

    const float* WtEv  = Wt;
    const float* WtEc  = Wt + 8192;
    const float* WtSv0 = Wt + 16384;
    const float* WtSv1 = WtSv0 + 16384;
    const float* WtSc0 = WtSv1 + 16384;
    const float* WtSc1 = WtSc0 + 16384;
    const float* WtCpl = WtSc1 + 16384;
    const float* WtCpr = WtCpl + 16384;
    const float* WtCnl = WtCpr + 16384;
    const float* WtCnr = WtCnl + 16384;

    const int NB = (NN + 255) / 256;      // 196 scan blocks
    const int EB = (EE + 255) / 256;

    transpose_all<<<576, 256, 0, stream>>>(W_var_emb, W_cls_emb, sv_W, sc_W,
                                           cp_Wl, cp_Wr, cn_Wl, cn_Wr, Wt);
    embed_ln<<<NN / 8, 128, 0, stream>>>(x_var, WtEv, ln_var_g, ln_var_b, var_pw, sv_b, F, C);
    embed_ln<<<NN / 8, 128, 0, stream>>>(x_cls, WtEc, ln_cls_g, ln_cls_b, cls_pw, sc_b, G, D);
    init_out<<<(2 * NN * 128 + 255) / 256, 256, 0, stream>>>(cp_b, cn_b, out0);

    auto build_csr = [&](const int* srcI, const int* dstI) {
        zero_int<<<NB, 256, 0, stream>>>(counts, NN);
        hist_k<<<EB, 256, 0, stream>>>(dstI, counts);
        scan_part<<<NB, 256, 0, stream>>>(counts, blockSums);
        scan_tops<<<1, 64, 0, stream>>>(blockSums, NB);
        scan_final<<<NB, 256, 0, stream>>>(counts, blockSums, starts, cursor);
        scatter_k<<<EB, 256, 0, stream>>>(srcI, dstI, cursor, sortedSrc);
    };

    // ---- self attention ----
    for (int side = 0; side < 2; ++side) {
        const float* h    = side ? D : C;
        float*       acc  = side ? G : F;
        const int*   mp   = side ? mp_cls : mp_var;
        const float* attl = side ? sc_al : sv_al;
        const float* attr = side ? sc_ar : sv_ar;
        const float* pw   = side ? cls_pw : var_pw;
        const float* Wts[2] = { side ? WtSc0 : WtSv0, side ? WtSc1 : WtSv1 };
        for (int p = 0; p < 2; ++p) {
            const int* srcI = mp + (size_t)p * 2 * EE;
            const int* dstI = srcI + EE;
            gemm128<<<NN / 8, 128, 0, stream>>>(h, Wts[p], XL);
            node_dots<<<NN / 4, 256, 0, stream>>>(XL, attl + p * 512, attr + p * 512, dl, dr);
            build_csr(srcI, dstI);
            agg_sorted<<<NN, 128, 0, stream>>>(starts, counts, sortedSrc,
                                               dl, dr, XL, pw, p, 1, acc);
        }
    }

    // ---- cross attention ----
    for (int sign = 0; sign < 2; ++sign) {
        const int* adj  = sign ? adj_neg : adj_pos;
        const int* cI   = adj;
        const int* vI   = adj + EE;
        const float* Wl   = sign ? WtCnl : WtCpl;
        const float* Wr   = sign ? WtCnr : WtCpr;
        const float* attl = sign ? cn_al : cp_al;
        const float* attr = sign ? cn_ar : cp_ar;
        gemm128<<<NN / 8, 128, 0, stream>>>(F, Wl, C);
        gemm128<<<NN / 8, 128, 0, stream>>>(G, Wr, D);
        node_dots<<<NN / 4, 256, 0, stream>>>(C, attl, attr, dl, dr);    // dl=al, dr=ar_
        node_dots<<<NN / 4, 256, 0, stream>>>(D, attl, attr, dl2, dr2);  // dl2=al_, dr2=ar
        // var direction: dst=v, a_dst=al, a_src=ar, feats=xr(D) -> out0
        build_csr(cI, vI);
        agg_sorted<<<NN, 128, 0, stream>>>(starts, counts, sortedSrc,
                                           dl, dr2, D, nullptr, 0, 0, out0);
        // cls direction: dst=c, a_dst=al_, a_src=ar_, feats=xl(C) -> out1
        build_csr(vI, cI);
        agg_sorted<<<NN, 128, 0, stream>>>(starts, counts, sortedSrc,
                                           dl2, dr, C, nullptr, 0, 0, out1);
    }
}

// Round 3
// 2077.512 us; speedup vs baseline: 2.0272x; 1.0742x over previous
//
#include <hip/hip_runtime.h>
#include <hip/hip_bf16.h>

#define NN 50000
#define EE 640000
#define NEG 0.2f
#define CAP 128          // per-segment LDS cache; degree ~ Poisson(12.8), P(k>128) ~ 0

struct Ptr8 { const int* p[8]; };

__device__ __forceinline__ unsigned short f2bf(float x) {
    unsigned b = __float_as_uint(x);
    b = b + 0x7fffu + ((b >> 16) & 1u);   // RNE
    return (unsigned short)(b >> 16);
}

// ---------------- transpose all weight matrices into ws ----------------
__global__ void transpose_all(const float* __restrict__ wev, const float* __restrict__ wec,
                              const float* __restrict__ svW, const float* __restrict__ scW,
                              const float* __restrict__ cpl, const float* __restrict__ cpr,
                              const float* __restrict__ cnl, const float* __restrict__ cnr,
                              float* __restrict__ out)
{
    int i = blockIdx.x * 256 + threadIdx.x;
    if (i < 8192)  { out[i] = wev[(i & 127) * 64 + (i >> 7)]; return; }
    if (i < 16384) { int j = i - 8192; out[i] = wec[(j & 127) * 64 + (j >> 7)]; return; }
    int t = i - 16384;
    int m = t >> 14, j = t & 16383;
    const float* src;
    switch (m) {
        case 0:  src = svW;         break;
        case 1:  src = svW + 16384; break;
        case 2:  src = scW;         break;
        case 3:  src = scW + 16384; break;
        case 4:  src = cpl;         break;
        case 5:  src = cpr;         break;
        case 6:  src = cnl;         break;
        default: src = cnr;         break;
    }
    out[i] = src[(j & 127) * 128 + (j >> 7)];
}

// ---------------- embedding GEMM + LayerNorm ----------------
__global__ void embed_ln(const float* __restrict__ x, const float* __restrict__ Wt,
                         const float* __restrict__ g, const float* __restrict__ b,
                         const float* __restrict__ pw, const float* __restrict__ sb,
                         float* __restrict__ F, float* __restrict__ C)
{
    __shared__ float lx[8][64];
    __shared__ float red[2][8][2];
    int c = threadIdx.x;
    int n0 = blockIdx.x * 8;
    for (int t = c; t < 8 * 64; t += 128) {
        lx[t >> 6][t & 63] = x[(size_t)(n0 + (t >> 6)) * 64 + (t & 63)];
    }
    __syncthreads();
    float acc[8];
#pragma unroll
    for (int m = 0; m < 8; m++) acc[m] = 0.f;
    for (int k = 0; k < 64; k++) {
        float w = Wt[k * 128 + c];
#pragma unroll
        for (int m = 0; m < 8; m++) acc[m] += lx[m][k] * w;
    }
    int lane = c & 63, wv = c >> 6;
#pragma unroll
    for (int m = 0; m < 8; m++) {
        float s1 = acc[m], s2 = acc[m] * acc[m];
        for (int off = 32; off; off >>= 1) { s1 += __shfl_xor(s1, off); s2 += __shfl_xor(s2, off); }
        if (lane == 0) { red[wv][m][0] = s1; red[wv][m][1] = s2; }
    }
    __syncthreads();
    float biassum = pw[0] * sb[c] + pw[1] * sb[128 + c];
    float gg = g[c], bb = b[c];
#pragma unroll
    for (int m = 0; m < 8; m++) {
        float s1 = red[0][m][0] + red[1][m][0];
        float s2 = red[0][m][1] + red[1][m][1];
        float mu  = s1 * (1.f / 128.f);
        float var = s2 * (1.f / 128.f) - mu * mu;
        float inv = rsqrtf(var + 1e-5f);
        float v = acc[m];
        size_t idx = (size_t)(n0 + m) * 128 + c;
        F[idx] = v + biassum;
        C[idx] = (v - mu) * inv * gg + bb;
    }
}

// ---------------- fused 128x128 projection + attention dots + bf16 store ----------------
// out_bf[n][c] = bf16( (in @ Wt)[n][c] );  dl[n][h] = row·attL[:,h];  dr likewise
__global__ void gemm_dots(const float* __restrict__ in, const float* __restrict__ Wt,
                          const float* __restrict__ attL, const float* __restrict__ attR,
                          unsigned short* __restrict__ out_bf,
                          float* __restrict__ dl, float* __restrict__ dr)
{
    __shared__ float lx[8][128];
    __shared__ float red[2][8][8];
    int c = threadIdx.x;
    int n0 = blockIdx.x * 8;
    for (int t = c; t < 8 * 128; t += 128) {
        lx[t >> 7][t & 127] = in[(size_t)n0 * 128 + t];
    }
    __syncthreads();
    float acc[8];
#pragma unroll
    for (int m = 0; m < 8; m++) acc[m] = 0.f;
    for (int k = 0; k < 128; k++) {
        float w = Wt[k * 128 + c];
#pragma unroll
        for (int m = 0; m < 8; m++) acc[m] += lx[m][k] * w;
    }
    float al[4], ar[4];
#pragma unroll
    for (int h = 0; h < 4; h++) { al[h] = attL[c * 4 + h]; ar[h] = attR[c * 4 + h]; }
    int lane = c & 63, wv = c >> 6;
#pragma unroll
    for (int m = 0; m < 8; m++) {
        out_bf[(size_t)(n0 + m) * 128 + c] = f2bf(acc[m]);
        float v[8];
#pragma unroll
        for (int h = 0; h < 4; h++) { v[h] = acc[m] * al[h]; v[4 + h] = acc[m] * ar[h]; }
        for (int off = 32; off; off >>= 1) {
#pragma unroll
            for (int j = 0; j < 8; j++) v[j] += __shfl_xor(v[j], off);
        }
        if (lane == 0) {
#pragma unroll
            for (int j = 0; j < 8; j++) red[wv][m][j] = v[j];
        }
    }
    __syncthreads();
    if (c < 64) {
        int m = c >> 3, j = c & 7;
        float v = red[0][m][j] + red[1][m][j];
        int n = n0 + m;
        if (j < 4) dl[n * 4 + j] = v;
        else       dr[n * 4 + (j - 4)] = v;
    }
}

// ---------------- init output with biases ----------------
__global__ void init_out(const float* __restrict__ b0, const float* __restrict__ b1,
                         float* __restrict__ out)
{
    int i = blockIdx.x * 256 + threadIdx.x;
    if (i < 2 * NN * 128) out[i] = b0[i & 127] + b1[i & 127];
}

// ---------------- batched counting sort (8 edge lists) ----------------
__global__ void zero8(int* __restrict__ p)
{
    int i = blockIdx.x * 256 + threadIdx.x;
    if (i < 8 * NN) p[i] = 0;
}

#define EB 2500   // EE/256
#define NB 196    // ceil(NN/256)

__global__ void hist8(Ptr8 dst, int* __restrict__ counts8)
{
    int b = blockIdx.x / EB;
    int e = (blockIdx.x % EB) * 256 + threadIdx.x;
    if (e < EE) atomicAdd(&counts8[b * NN + dst.p[b][e]], 1);
}

__global__ void scan_part8(const int* __restrict__ counts8, int* __restrict__ blockSums8)
{
    __shared__ int red[4];
    int seg = blockIdx.x / NB, lb = blockIdx.x % NB;
    int t = threadIdx.x;
    int i = lb * 256 + t;
    int v = (i < NN) ? counts8[seg * NN + i] : 0;
    for (int off = 32; off; off >>= 1) v += __shfl_xor(v, off);
    if ((t & 63) == 0) red[t >> 6] = v;
    __syncthreads();
    if (t == 0) blockSums8[seg * 256 + lb] = red[0] + red[1] + red[2] + red[3];
}

__global__ void scan_tops8(int* __restrict__ blockSums8)
{
    if (threadIdx.x != 0) return;
    int seg = blockIdx.x;
    int acc = 0;
    for (int i = 0; i < NB; i++) {
        int t = blockSums8[seg * 256 + i];
        blockSums8[seg * 256 + i] = acc;
        acc += t;
    }
}

__global__ void scan_final8(const int* __restrict__ counts8, const int* __restrict__ blockSums8,
                            int* __restrict__ starts8, int* __restrict__ cursor8)
{
    __shared__ int sh[256];
    int seg = blockIdx.x / NB, lb = blockIdx.x % NB;
    int t = threadIdx.x;
    int i = lb * 256 + t;
    int v = (i < NN) ? counts8[seg * NN + i] : 0;
    sh[t] = v;
    __syncthreads();
    for (int off = 1; off < 256; off <<= 1) {
        int x = (t >= off) ? sh[t - off] : 0;
        __syncthreads();
        sh[t] += x;
        __syncthreads();
    }
    int excl = sh[t] - v + blockSums8[seg * 256 + lb];
    if (i < NN) { starts8[seg * NN + i] = excl; cursor8[seg * NN + i] = excl; }
}

__global__ void scatter8(Ptr8 src, Ptr8 dst, int* __restrict__ cursor8,
                         int* __restrict__ sorted8)
{
    int b = blockIdx.x / EB;
    int e = (blockIdx.x % EB) * 256 + threadIdx.x;
    if (e >= EE) return;
    int d = dst.p[b][e];
    int pos = atomicAdd(&cursor8[b * NN + d], 1);
    sorted8[(size_t)b * EE + pos] = src.p[b][e];
}

// ---------------- fused segment softmax + bf16 gather aggregation ----------------
__global__ __launch_bounds__(128) void agg_sorted(
    const int* __restrict__ starts, const int* __restrict__ counts,
    const int* __restrict__ sortedSrc,
    const float* __restrict__ a_dst, const float* __restrict__ a_src,
    const unsigned short* __restrict__ feats,   // bf16 bits [NN][128]
    const float* __restrict__ pw, int pwi, int hasLoop,
    float* __restrict__ acc)
{
    __shared__ float4 exSh[CAP];
    __shared__ int    sSh[CAP];
    __shared__ float  wSh[CAP];
    __shared__ float  red[2][4];
    __shared__ float  denSh[4];
    __shared__ float  cmb[2][64][2];

    int d = blockIdx.x;
    int t = threadIdx.x;
    int base = starts[d];
    int k = counts[d];
    int kTot = k + hasLoop;

    float4 ad = *(const float4*)(a_dst + (size_t)d * 4);
    float p0 = 0.f, p1 = 0.f, p2 = 0.f, p3 = 0.f;
    for (int i = t; i < kTot; i += 128) {
        int s = (i < k) ? sortedSrc[base + i] : d;
        float4 as = *(const float4*)(a_src + (size_t)s * 4);
        float v0 = ad.x + as.x, v1 = ad.y + as.y, v2 = ad.z + as.z, v3 = ad.w + as.w;
        v0 = v0 > 0.f ? v0 : NEG * v0;
        v1 = v1 > 0.f ? v1 : NEG * v1;
        v2 = v2 > 0.f ? v2 : NEG * v2;
        v3 = v3 > 0.f ? v3 : NEG * v3;
        float e0 = __expf(v0), e1 = __expf(v1), e2 = __expf(v2), e3 = __expf(v3);
        if (i < CAP) { exSh[i] = make_float4(e0, e1, e2, e3); sSh[i] = s; }
        p0 += e0; p1 += e1; p2 += e2; p3 += e3;
    }
    for (int off = 32; off; off >>= 1) {
        p0 += __shfl_xor(p0, off); p1 += __shfl_xor(p1, off);
        p2 += __shfl_xor(p2, off); p3 += __shfl_xor(p3, off);
    }
    int lane = t & 63, half = t >> 6;
    if (lane == 0) { red[half][0] = p0; red[half][1] = p1; red[half][2] = p2; red[half][3] = p3; }
    __syncthreads();
    if (t < 4) denSh[t] = red[0][t] + red[1][t];
    __syncthreads();

    float scale = 0.25f * (pw ? pw[pwi] : 1.0f);
    float d0 = denSh[0] + 1e-16f, d1 = denSh[1] + 1e-16f;
    float d2 = denSh[2] + 1e-16f, d3 = denSh[3] + 1e-16f;
    if (t < CAP && t < kTot) {
        float4 ex = exSh[t];
        wSh[t] = scale * (ex.x / d0 + ex.y / d1 + ex.z / d2 + ex.w / d3);
    }
    __syncthreads();

    // half-block per edge-slot; each lane covers channels 2*lane, 2*lane+1 (bf16x2 = 4B loads)
    float a0 = 0.f, a1 = 0.f;
    for (int j = half; j < kTot; j += 2) {
        float w; int s;
        if (j < CAP) { w = wSh[j]; s = sSh[j]; }
        else {  // degree > 128 fallback (practically never)
            s = (j < k) ? sortedSrc[base + j] : d;
            float4 as = *(const float4*)(a_src + (size_t)s * 4);
            float v0 = ad.x + as.x, v1 = ad.y + as.y, v2 = ad.z + as.z, v3 = ad.w + as.w;
            v0 = v0 > 0.f ? v0 : NEG * v0;
            v1 = v1 > 0.f ? v1 : NEG * v1;
            v2 = v2 > 0.f ? v2 : NEG * v2;
            v3 = v3 > 0.f ? v3 : NEG * v3;
            w = scale * (__expf(v0) / d0 + __expf(v1) / d1 + __expf(v2) / d2 + __expf(v3) / d3);
        }
        unsigned v = *(const unsigned*)(feats + (size_t)s * 128 + 2 * lane);
        float f0 = __uint_as_float(v << 16);
        float f1 = __uint_as_float(v & 0xffff0000u);
        a0 += w * f0; a1 += w * f1;
    }
    cmb[half][lane][0] = a0; cmb[half][lane][1] = a1;
    __syncthreads();
    if (t < 64) {
        size_t o = (size_t)d * 128 + 2 * t;
        float2 prev = *(const float2*)(acc + o);
        prev.x += cmb[0][t][0] + cmb[1][t][0];
        prev.y += cmb[0][t][1] + cmb[1][t][1];
        *(float2*)(acc + o) = prev;
    }
}

extern "C" void kernel_launch(void* const* d_in, const int* in_sizes, int n_in,
                              void* d_out, int out_size, void* d_ws, size_t ws_size,
                              hipStream_t stream)
{
    const float* x_var   = (const float*)d_in[0];
    const float* x_cls   = (const float*)d_in[1];
    const int*   mp_var  = (const int*)d_in[2];
    const int*   mp_cls  = (const int*)d_in[3];
    const int*   adj_pos = (const int*)d_in[4];
    const int*   adj_neg = (const int*)d_in[5];
    const float* W_var_emb = (const float*)d_in[6];
    const float* W_cls_emb = (const float*)d_in[7];
    const float* ln_var_g = (const float*)d_in[8];
    const float* ln_var_b = (const float*)d_in[9];
    const float* ln_cls_g = (const float*)d_in[10];
    const float* ln_cls_b = (const float*)d_in[11];
    const float* var_pw = (const float*)d_in[12];
    const float* cls_pw = (const float*)d_in[13];
    const float* sv_W  = (const float*)d_in[14];
    const float* sv_al = (const float*)d_in[15];
    const float* sv_ar = (const float*)d_in[16];
    const float* sv_b  = (const float*)d_in[17];
    const float* sc_W  = (const float*)d_in[18];
    const float* sc_al = (const float*)d_in[19];
    const float* sc_ar = (const float*)d_in[20];
    const float* sc_b  = (const float*)d_in[21];
    const float* cp_Wl = (const float*)d_in[22];
    const float* cp_Wr = (const float*)d_in[23];
    const float* cp_al = (const float*)d_in[24];
    const float* cp_ar = (const float*)d_in[25];
    const float* cp_b  = (const float*)d_in[26];
    const float* cn_Wl = (const float*)d_in[27];
    const float* cn_Wr = (const float*)d_in[28];
    const float* cn_al = (const float*)d_in[29];
    const float* cn_ar = (const float*)d_in[30];
    const float* cn_b  = (const float*)d_in[31];

    float* out0 = (float*)d_out;
    float* out1 = out0 + (size_t)NN * 128;

    float* ws = (float*)d_ws;
    size_t off = 0;
    auto alloc = [&](size_t n) { float* p = ws + off; off += n; return p; };
    float* Wt  = alloc(147456);
    float* F   = alloc((size_t)NN * 128);
    float* G   = alloc((size_t)NN * 128);
    float* C   = alloc((size_t)NN * 128);   // hv
    float* D   = alloc((size_t)NN * 128);   // hc
    unsigned short* B1 = (unsigned short*)alloc((size_t)NN * 64);  // bf16 [NN][128]
    unsigned short* B2 = (unsigned short*)alloc((size_t)NN * 64);
    float* dl   = alloc(NN * 4);
    float* dr   = alloc(NN * 4);
    float* dl2  = alloc(NN * 4);
    float* dr2  = alloc(NN * 4);
    int* counts8    = (int*)alloc(8 * NN);
    int* starts8    = (int*)alloc(8 * NN);
    int* cursor8    = (int*)alloc(8 * NN);
    int* blockSums8 = (int*)alloc(8 * 256);
    int* sorted8    = (int*)alloc((size_t)8 * EE);

    const float* WtEv  = Wt;
    const float* WtEc  = Wt + 8192;
    const float* WtSv0 = Wt + 16384;
    const float* WtSv1 = WtSv0 + 16384;
    const float* WtSc0 = WtSv1 + 16384;
    const float* WtSc1 = WtSc0 + 16384;
    const float* WtCpl = WtSc1 + 16384;
    const float* WtCpr = WtCpl + 16384;
    const float* WtCnl = WtCpr + 16384;
    const float* WtCnr = WtCnl + 16384;

    // edge-list table: 0..3 = self (mp_var p0,p1, mp_cls p0,p1); 4 = pos var-dir;
    // 5 = pos cls-dir; 6 = neg var-dir; 7 = neg cls-dir
    Ptr8 srcP, dstP;
    srcP.p[0] = mp_var;            dstP.p[0] = mp_var + EE;
    srcP.p[1] = mp_var + 2 * EE;   dstP.p[1] = mp_var + 3 * EE;
    srcP.p[2] = mp_cls;            dstP.p[2] = mp_cls + EE;
    srcP.p[3] = mp_cls + 2 * EE;   dstP.p[3] = mp_cls + 3 * EE;
    srcP.p[4] = adj_pos;           dstP.p[4] = adj_pos + EE;   // c -> v
    srcP.p[5] = adj_pos + EE;      dstP.p[5] = adj_pos;        // v -> c
    srcP.p[6] = adj_neg;           dstP.p[6] = adj_neg + EE;
    srcP.p[7] = adj_neg + EE;      dstP.p[7] = adj_neg;

    // ---- batched CSR build (depends only on inputs) ----
    zero8<<<(8 * NN + 255) / 256, 256, 0, stream>>>(counts8);
    hist8<<<8 * EB, 256, 0, stream>>>(dstP, counts8);
    scan_part8<<<8 * NB, 256, 0, stream>>>(counts8, blockSums8);
    scan_tops8<<<8, 64, 0, stream>>>(blockSums8);
    scan_final8<<<8 * NB, 256, 0, stream>>>(counts8, blockSums8, starts8, cursor8);
    scatter8<<<8 * EB, 256, 0, stream>>>(srcP, dstP, cursor8, sorted8);

    transpose_all<<<576, 256, 0, stream>>>(W_var_emb, W_cls_emb, sv_W, sc_W,
                                           cp_Wl, cp_Wr, cn_Wl, cn_Wr, Wt);
    embed_ln<<<NN / 8, 128, 0, stream>>>(x_var, WtEv, ln_var_g, ln_var_b, var_pw, sv_b, F, C);
    embed_ln<<<NN / 8, 128, 0, stream>>>(x_cls, WtEc, ln_cls_g, ln_cls_b, cls_pw, sc_b, G, D);
    init_out<<<(2 * NN * 128 + 255) / 256, 256, 0, stream>>>(cp_b, cn_b, out0);

    // ---- self attention ----
    for (int side = 0; side < 2; ++side) {
        const float* h    = side ? D : C;
        float*       acc  = side ? G : F;
        const float* attl = side ? sc_al : sv_al;
        const float* attr = side ? sc_ar : sv_ar;
        const float* pw   = side ? cls_pw : var_pw;
        const float* Wts[2] = { side ? WtSc0 : WtSv0, side ? WtSc1 : WtSv1 };
        for (int p = 0; p < 2; ++p) {
            int seg = side * 2 + p;
            gemm_dots<<<NN / 8, 128, 0, stream>>>(h, Wts[p], attl + p * 512, attr + p * 512,
                                                  B1, dl, dr);
            agg_sorted<<<NN, 128, 0, stream>>>(starts8 + seg * NN, counts8 + seg * NN,
                                               sorted8 + (size_t)seg * EE,
                                               dl, dr, B1, pw, p, 1, acc);
        }
    }

    // ---- cross attention ----
    for (int sign = 0; sign < 2; ++sign) {
        const float* Wl   = sign ? WtCnl : WtCpl;
        const float* Wr   = sign ? WtCnr : WtCpr;
        const float* attl = sign ? cn_al : cp_al;
        const float* attr = sign ? cn_ar : cp_ar;
        int segV = 4 + sign * 2;       // var-direction CSR
        int segC = 5 + sign * 2;       // cls-direction CSR
        gemm_dots<<<NN / 8, 128, 0, stream>>>(F, Wl, attl, attr, B1, dl, dr);    // xl: dl=al, dr=ar_
        gemm_dots<<<NN / 8, 128, 0, stream>>>(G, Wr, attl, attr, B2, dl2, dr2);  // xr: dl2=al_, dr2=ar
        // var direction: dst=v, a_dst=al(dl), a_src=ar(dr2), feats=xr(B2) -> out0
        agg_sorted<<<NN, 128, 0, stream>>>(starts8 + segV * NN, counts8 + segV * NN,
                                           sorted8 + (size_t)segV * EE,
                                           dl, dr2, B2, nullptr, 0, 0, out0);
        // cls direction: dst=c, a_dst=al_(dl2), a_src=ar_(dr), feats=xl(B1) -> out1
        agg_sorted<<<NN, 128, 0, stream>>>(starts8 + segC * NN, counts8 + segC * NN,
                                           sorted8 + (size_t)segC * EE,
                                           dl2, dr, B1, nullptr, 0, 0, out1);
    }
}

// Round 4
// 1578.925 us; speedup vs baseline: 2.6674x; 1.3158x over previous
//
#include <hip/hip_runtime.h>
#include <hip/hip_bf16.h>

#define NN 50000
#define EE 640000
#define NEG 0.2f
#define CAP 128          // per-segment LDS cache; degree ~ Poisson(12.8), P(k>128) ~ 0

#define BSH 7                          // 128 dsts per bucket
#define NBKT 391                       // ceil(NN/128)
#define CHUNKA 8192
#define PA_B 79                        // ceil(EE/CHUNKA)

struct Ptr8 { const int* p[8]; };

__device__ __forceinline__ unsigned short f2bf(float x) {
    unsigned b = __float_as_uint(x);
    b = b + 0x7fffu + ((b >> 16) & 1u);   // RNE
    return (unsigned short)(b >> 16);
}

// ---------------- transpose all weight matrices into ws ----------------
__global__ void transpose_all(const float* __restrict__ wev, const float* __restrict__ wec,
                              const float* __restrict__ svW, const float* __restrict__ scW,
                              const float* __restrict__ cpl, const float* __restrict__ cpr,
                              const float* __restrict__ cnl, const float* __restrict__ cnr,
                              float* __restrict__ out)
{
    int i = blockIdx.x * 256 + threadIdx.x;
    if (i < 8192)  { out[i] = wev[(i & 127) * 64 + (i >> 7)]; return; }
    if (i < 16384) { int j = i - 8192; out[i] = wec[(j & 127) * 64 + (j >> 7)]; return; }
    int t = i - 16384;
    int m = t >> 14, j = t & 16383;
    const float* src;
    switch (m) {
        case 0:  src = svW;         break;
        case 1:  src = svW + 16384; break;
        case 2:  src = scW;         break;
        case 3:  src = scW + 16384; break;
        case 4:  src = cpl;         break;
        case 5:  src = cpr;         break;
        case 6:  src = cnl;         break;
        default: src = cnr;         break;
    }
    out[i] = src[(j & 127) * 128 + (j >> 7)];
}

// ---------------- embedding GEMM + LayerNorm ----------------
__global__ void embed_ln(const float* __restrict__ x, const float* __restrict__ Wt,
                         const float* __restrict__ g, const float* __restrict__ b,
                         const float* __restrict__ pw, const float* __restrict__ sb,
                         float* __restrict__ F, float* __restrict__ C)
{
    __shared__ float lx[8][64];
    __shared__ float red[2][8][2];
    int c = threadIdx.x;
    int n0 = blockIdx.x * 8;
    for (int t = c; t < 8 * 64; t += 128) {
        lx[t >> 6][t & 63] = x[(size_t)(n0 + (t >> 6)) * 64 + (t & 63)];
    }
    __syncthreads();
    float acc[8];
#pragma unroll
    for (int m = 0; m < 8; m++) acc[m] = 0.f;
    for (int k = 0; k < 64; k++) {
        float w = Wt[k * 128 + c];
#pragma unroll
        for (int m = 0; m < 8; m++) acc[m] += lx[m][k] * w;
    }
    int lane = c & 63, wv = c >> 6;
#pragma unroll
    for (int m = 0; m < 8; m++) {
        float s1 = acc[m], s2 = acc[m] * acc[m];
        for (int off = 32; off; off >>= 1) { s1 += __shfl_xor(s1, off); s2 += __shfl_xor(s2, off); }
        if (lane == 0) { red[wv][m][0] = s1; red[wv][m][1] = s2; }
    }
    __syncthreads();
    float biassum = pw[0] * sb[c] + pw[1] * sb[128 + c];
    float gg = g[c], bb = b[c];
#pragma unroll
    for (int m = 0; m < 8; m++) {
        float s1 = red[0][m][0] + red[1][m][0];
        float s2 = red[0][m][1] + red[1][m][1];
        float mu  = s1 * (1.f / 128.f);
        float var = s2 * (1.f / 128.f) - mu * mu;
        float inv = rsqrtf(var + 1e-5f);
        float v = acc[m];
        size_t idx = (size_t)(n0 + m) * 128 + c;
        F[idx] = v + biassum;
        C[idx] = (v - mu) * inv * gg + bb;
    }
}

// ---------------- fused 128x128 projection + attention dots + bf16 store ----------------
__global__ void gemm_dots(const float* __restrict__ in, const float* __restrict__ Wt,
                          const float* __restrict__ attL, const float* __restrict__ attR,
                          unsigned short* __restrict__ out_bf,
                          float* __restrict__ dl, float* __restrict__ dr)
{
    __shared__ float lx[8][128];
    __shared__ float red[2][8][8];
    int c = threadIdx.x;
    int n0 = blockIdx.x * 8;
    for (int t = c; t < 8 * 128; t += 128) {
        lx[t >> 7][t & 127] = in[(size_t)n0 * 128 + t];
    }
    __syncthreads();
    float acc[8];
#pragma unroll
    for (int m = 0; m < 8; m++) acc[m] = 0.f;
    for (int k = 0; k < 128; k++) {
        float w = Wt[k * 128 + c];
#pragma unroll
        for (int m = 0; m < 8; m++) acc[m] += lx[m][k] * w;
    }
    float al[4], ar[4];
#pragma unroll
    for (int h = 0; h < 4; h++) { al[h] = attL[c * 4 + h]; ar[h] = attR[c * 4 + h]; }
    int lane = c & 63, wv = c >> 6;
#pragma unroll
    for (int m = 0; m < 8; m++) {
        out_bf[(size_t)(n0 + m) * 128 + c] = f2bf(acc[m]);
        float v[8];
#pragma unroll
        for (int h = 0; h < 4; h++) { v[h] = acc[m] * al[h]; v[4 + h] = acc[m] * ar[h]; }
        for (int off = 32; off; off >>= 1) {
#pragma unroll
            for (int j = 0; j < 8; j++) v[j] += __shfl_xor(v[j], off);
        }
        if (lane == 0) {
#pragma unroll
            for (int j = 0; j < 8; j++) red[wv][m][j] = v[j];
        }
    }
    __syncthreads();
    if (c < 64) {
        int m = c >> 3, j = c & 7;
        float v = red[0][m][j] + red[1][m][j];
        int n = n0 + m;
        if (j < 4) dl[n * 4 + j] = v;
        else       dr[n * 4 + (j - 4)] = v;
    }
}

// ---------------- init output with biases ----------------
__global__ void init_out(const float* __restrict__ b0, const float* __restrict__ b1,
                         float* __restrict__ out)
{
    int i = blockIdx.x * 256 + threadIdx.x;
    if (i < 2 * NN * 128) out[i] = b0[i & 127] + b1[i & 127];
}

// ================= two-level bucket sort (8 edge lists) =================
__global__ void zero_bcnt(int* __restrict__ p)
{
    int i = blockIdx.x * 256 + threadIdx.x;
    if (i < 8 * NBKT) p[i] = 0;
}

// per-chunk LDS histogram over 128-dst buckets -> global bucket counts
__global__ void bucket_count(Ptr8 dst, int* __restrict__ bcnt)
{
    __shared__ int h[NBKT];
    int l = blockIdx.x / PA_B, cb = blockIdx.x % PA_B;
    const int* dp = dst.p[l];
    for (int i = threadIdx.x; i < NBKT; i += 256) h[i] = 0;
    __syncthreads();
    int e0 = cb * CHUNKA;
    for (int i = threadIdx.x; i < CHUNKA; i += 256) {
        int e = e0 + i;
        if (e < EE) atomicAdd(&h[dp[e] >> BSH], 1);
    }
    __syncthreads();
    for (int i = threadIdx.x; i < NBKT; i += 256)
        if (h[i]) atomicAdd(&bcnt[l * NBKT + i], h[i]);
}

// exclusive scan of bucket counts per list -> bstart (with sentinel) and working cursor
__global__ void bucket_scan(const int* __restrict__ bcnt, int* __restrict__ bstart,
                            int* __restrict__ bcur)
{
    __shared__ int sh[NBKT];
    int l = blockIdx.x;
    for (int i = threadIdx.x; i < NBKT; i += 256) sh[i] = bcnt[l * NBKT + i];
    __syncthreads();
    if (threadIdx.x == 0) {
        int acc = 0;
        for (int i = 0; i < NBKT; i++) { int t = sh[i]; sh[i] = acc; acc += t; }
    }
    __syncthreads();
    for (int i = threadIdx.x; i < NBKT; i += 256) {
        bstart[l * (NBKT + 1) + i] = sh[i];
        bcur[l * NBKT + i] = sh[i];
    }
    if (threadIdx.x == 0) bstart[l * (NBKT + 1) + NBKT] = EE;
}

// bin edges into bucket runs; each block writes contiguous per-bucket runs (packed src<<16|dst)
__global__ void bucket_place(Ptr8 src, Ptr8 dst, int* __restrict__ bcur,
                             unsigned* __restrict__ recs)
{
    __shared__ int h[NBKT];
    __shared__ int base[NBKT];
    int l = blockIdx.x / PA_B, cb = blockIdx.x % PA_B;
    const int* sp = src.p[l];
    const int* dp = dst.p[l];
    for (int i = threadIdx.x; i < NBKT; i += 256) h[i] = 0;
    __syncthreads();
    int e0 = cb * CHUNKA;
    for (int i = threadIdx.x; i < CHUNKA; i += 256) {
        int e = e0 + i;
        if (e < EE) atomicAdd(&h[dp[e] >> BSH], 1);
    }
    __syncthreads();
    for (int i = threadIdx.x; i < NBKT; i += 256) {
        int c = h[i];
        base[i] = c ? atomicAdd(&bcur[l * NBKT + i], c) : 0;
        h[i] = 0;                       // reuse as local cursor
    }
    __syncthreads();
    unsigned* rl = recs + (size_t)l * EE;
    for (int i = threadIdx.x; i < CHUNKA; i += 256) {
        int e = e0 + i;
        if (e >= EE) continue;
        int d = dp[e];
        int b = d >> BSH;
        int pos = base[b] + atomicAdd(&h[b], 1);
        rl[pos] = ((unsigned)sp[e] << 16) | (unsigned)d;
    }
}

// one block per bucket: exact per-dst placement within block-owned window.
// Also emits starts8/counts8 (replaces the old histogram+scan pipeline).
__global__ void bucket_final(const unsigned* __restrict__ recs,
                             const int* __restrict__ bstart,
                             int* __restrict__ starts8, int* __restrict__ counts8,
                             unsigned short* __restrict__ sortedU)
{
    __shared__ int cnt[128];
    __shared__ int cur[128];
    int l = blockIdx.x / NBKT, b = blockIdx.x % NBKT;
    int d0 = b << BSH;
    int nd = min(128, NN - d0);
    int ebase = bstart[l * (NBKT + 1) + b];
    int ecnt  = bstart[l * (NBKT + 1) + b + 1] - ebase;
    const unsigned* rp = recs + (size_t)l * EE + ebase;
    int t = threadIdx.x;
    if (t < 128) cnt[t] = 0;
    __syncthreads();
    for (int i = t; i < ecnt; i += 256)
        atomicAdd(&cnt[(rp[i] & 0xffffu) - d0], 1);
    __syncthreads();
    if (t == 0) {
        int acc = 0;
        for (int i = 0; i < 128; i++) { int c = cnt[i]; cur[i] = acc; acc += c; }
    }
    __syncthreads();
    if (t < nd) {
        starts8[l * NN + d0 + t] = ebase + cur[t];
        counts8[l * NN + d0 + t] = cnt[t];
    }
    __syncthreads();
    unsigned short* so = sortedU + (size_t)l * EE + ebase;
    for (int i = t; i < ecnt; i += 256) {
        unsigned r = rp[i];
        int dloc = (int)(r & 0xffffu) - d0;
        int pos = atomicAdd(&cur[dloc], 1);
        so[pos] = (unsigned short)(r >> 16);
    }
}

// ---------------- fused segment softmax + bf16 gather aggregation ----------------
__global__ __launch_bounds__(128) void agg_sorted(
    const int* __restrict__ starts, const int* __restrict__ counts,
    const unsigned short* __restrict__ sortedSrc,
    const float* __restrict__ a_dst, const float* __restrict__ a_src,
    const unsigned short* __restrict__ feats,   // bf16 bits [NN][128]
    const float* __restrict__ pw, int pwi, int hasLoop,
    float* __restrict__ acc)
{
    __shared__ float4 exSh[CAP];
    __shared__ int    sSh[CAP];
    __shared__ float  wSh[CAP];
    __shared__ float  red[2][4];
    __shared__ float  denSh[4];
    __shared__ float  cmb[2][64][2];

    int d = blockIdx.x;
    int t = threadIdx.x;
    int base = starts[d];
    int k = counts[d];
    int kTot = k + hasLoop;

    float4 ad = *(const float4*)(a_dst + (size_t)d * 4);
    float p0 = 0.f, p1 = 0.f, p2 = 0.f, p3 = 0.f;
    for (int i = t; i < kTot; i += 128) {
        int s = (i < k) ? (int)sortedSrc[base + i] : d;
        float4 as = *(const float4*)(a_src + (size_t)s * 4);
        float v0 = ad.x + as.x, v1 = ad.y + as.y, v2 = ad.z + as.z, v3 = ad.w + as.w;
        v0 = v0 > 0.f ? v0 : NEG * v0;
        v1 = v1 > 0.f ? v1 : NEG * v1;
        v2 = v2 > 0.f ? v2 : NEG * v2;
        v3 = v3 > 0.f ? v3 : NEG * v3;
        float e0 = __expf(v0), e1 = __expf(v1), e2 = __expf(v2), e3 = __expf(v3);
        if (i < CAP) { exSh[i] = make_float4(e0, e1, e2, e3); sSh[i] = s; }
        p0 += e0; p1 += e1; p2 += e2; p3 += e3;
    }
    for (int off = 32; off; off >>= 1) {
        p0 += __shfl_xor(p0, off); p1 += __shfl_xor(p1, off);
        p2 += __shfl_xor(p2, off); p3 += __shfl_xor(p3, off);
    }
    int lane = t & 63, half = t >> 6;
    if (lane == 0) { red[half][0] = p0; red[half][1] = p1; red[half][2] = p2; red[half][3] = p3; }
    __syncthreads();
    if (t < 4) denSh[t] = red[0][t] + red[1][t];
    __syncthreads();

    float scale = 0.25f * (pw ? pw[pwi] : 1.0f);
    float d0 = denSh[0] + 1e-16f, d1 = denSh[1] + 1e-16f;
    float d2 = denSh[2] + 1e-16f, d3 = denSh[3] + 1e-16f;
    if (t < CAP && t < kTot) {
        float4 ex = exSh[t];
        wSh[t] = scale * (ex.x / d0 + ex.y / d1 + ex.z / d2 + ex.w / d3);
    }
    __syncthreads();

    float a0 = 0.f, a1 = 0.f;
    for (int j = half; j < kTot; j += 2) {
        float w; int s;
        if (j < CAP) { w = wSh[j]; s = sSh[j]; }
        else {
            s = (j < k) ? (int)sortedSrc[base + j] : d;
            float4 as = *(const float4*)(a_src + (size_t)s * 4);
            float v0 = ad.x + as.x, v1 = ad.y + as.y, v2 = ad.z + as.z, v3 = ad.w + as.w;
            v0 = v0 > 0.f ? v0 : NEG * v0;
            v1 = v1 > 0.f ? v1 : NEG * v1;
            v2 = v2 > 0.f ? v2 : NEG * v2;
            v3 = v3 > 0.f ? v3 : NEG * v3;
            w = scale * (__expf(v0) / d0 + __expf(v1) / d1 + __expf(v2) / d2 + __expf(v3) / d3);
        }
        unsigned v = *(const unsigned*)(feats + (size_t)s * 128 + 2 * lane);
        float f0 = __uint_as_float(v << 16);
        float f1 = __uint_as_float(v & 0xffff0000u);
        a0 += w * f0; a1 += w * f1;
    }
    cmb[half][lane][0] = a0; cmb[half][lane][1] = a1;
    __syncthreads();
    if (t < 64) {
        size_t o = (size_t)d * 128 + 2 * t;
        float2 prev = *(const float2*)(acc + o);
        prev.x += cmb[0][t][0] + cmb[1][t][0];
        prev.y += cmb[0][t][1] + cmb[1][t][1];
        *(float2*)(acc + o) = prev;
    }
}

extern "C" void kernel_launch(void* const* d_in, const int* in_sizes, int n_in,
                              void* d_out, int out_size, void* d_ws, size_t ws_size,
                              hipStream_t stream)
{
    const float* x_var   = (const float*)d_in[0];
    const float* x_cls   = (const float*)d_in[1];
    const int*   mp_var  = (const int*)d_in[2];
    const int*   mp_cls  = (const int*)d_in[3];
    const int*   adj_pos = (const int*)d_in[4];
    const int*   adj_neg = (const int*)d_in[5];
    const float* W_var_emb = (const float*)d_in[6];
    const float* W_cls_emb = (const float*)d_in[7];
    const float* ln_var_g = (const float*)d_in[8];
    const float* ln_var_b = (const float*)d_in[9];
    const float* ln_cls_g = (const float*)d_in[10];
    const float* ln_cls_b = (const float*)d_in[11];
    const float* var_pw = (const float*)d_in[12];
    const float* cls_pw = (const float*)d_in[13];
    const float* sv_W  = (const float*)d_in[14];
    const float* sv_al = (const float*)d_in[15];
    const float* sv_ar = (const float*)d_in[16];
    const float* sv_b  = (const float*)d_in[17];
    const float* sc_W  = (const float*)d_in[18];
    const float* sc_al = (const float*)d_in[19];
    const float* sc_ar = (const float*)d_in[20];
    const float* sc_b  = (const float*)d_in[21];
    const float* cp_Wl = (const float*)d_in[22];
    const float* cp_Wr = (const float*)d_in[23];
    const float* cp_al = (const float*)d_in[24];
    const float* cp_ar = (const float*)d_in[25];
    const float* cp_b  = (const float*)d_in[26];
    const float* cn_Wl = (const float*)d_in[27];
    const float* cn_Wr = (const float*)d_in[28];
    const float* cn_al = (const float*)d_in[29];
    const float* cn_ar = (const float*)d_in[30];
    const float* cn_b  = (const float*)d_in[31];

    float* out0 = (float*)d_out;
    float* out1 = out0 + (size_t)NN * 128;

    float* ws = (float*)d_ws;
    size_t off = 0;
    auto alloc = [&](size_t n) { float* p = ws + off; off += n; return p; };
    float* Wt  = alloc(147456);
    float* F   = alloc((size_t)NN * 128);
    float* G   = alloc((size_t)NN * 128);
    float* C   = alloc((size_t)NN * 128);   // hv
    float* D   = alloc((size_t)NN * 128);   // hc
    unsigned short* B1 = (unsigned short*)alloc((size_t)NN * 64);  // bf16 [NN][128]
    unsigned short* B2 = (unsigned short*)alloc((size_t)NN * 64);
    float* dl   = alloc(NN * 4);
    float* dr   = alloc(NN * 4);
    float* dl2  = alloc(NN * 4);
    float* dr2  = alloc(NN * 4);
    int* counts8 = (int*)alloc(8 * NN);
    int* starts8 = (int*)alloc(8 * NN);
    int* bcnt    = (int*)alloc(8 * NBKT);
    int* bstart  = (int*)alloc(8 * (NBKT + 1));
    int* bcur    = (int*)alloc(8 * NBKT);
    unsigned* recs = (unsigned*)alloc((size_t)8 * EE);          // packed src<<16|dst
    unsigned short* sortedU = (unsigned short*)alloc((size_t)4 * EE); // 8*EE ushorts

    const float* WtEv  = Wt;
    const float* WtEc  = Wt + 8192;
    const float* WtSv0 = Wt + 16384;
    const float* WtSv1 = WtSv0 + 16384;
    const float* WtSc0 = WtSv1 + 16384;
    const float* WtSc1 = WtSc0 + 16384;
    const float* WtCpl = WtSc1 + 16384;
    const float* WtCpr = WtCpl + 16384;
    const float* WtCnl = WtCpr + 16384;
    const float* WtCnr = WtCnl + 16384;

    // edge-list table: 0..3 = self (mp_var p0,p1, mp_cls p0,p1); 4 = pos var-dir;
    // 5 = pos cls-dir; 6 = neg var-dir; 7 = neg cls-dir
    Ptr8 srcP, dstP;
    srcP.p[0] = mp_var;            dstP.p[0] = mp_var + EE;
    srcP.p[1] = mp_var + 2 * EE;   dstP.p[1] = mp_var + 3 * EE;
    srcP.p[2] = mp_cls;            dstP.p[2] = mp_cls + EE;
    srcP.p[3] = mp_cls + 2 * EE;   dstP.p[3] = mp_cls + 3 * EE;
    srcP.p[4] = adj_pos;           dstP.p[4] = adj_pos + EE;   // c -> v
    srcP.p[5] = adj_pos + EE;      dstP.p[5] = adj_pos;        // v -> c
    srcP.p[6] = adj_neg;           dstP.p[6] = adj_neg + EE;
    srcP.p[7] = adj_neg + EE;      dstP.p[7] = adj_neg;

    // ---- two-level bucket sort of all 8 edge lists ----
    zero_bcnt<<<(8 * NBKT + 255) / 256, 256, 0, stream>>>(bcnt);
    bucket_count<<<8 * PA_B, 256, 0, stream>>>(dstP, bcnt);
    bucket_scan<<<8, 256, 0, stream>>>(bcnt, bstart, bcur);
    bucket_place<<<8 * PA_B, 256, 0, stream>>>(srcP, dstP, bcur, recs);
    bucket_final<<<8 * NBKT, 256, 0, stream>>>(recs, bstart, starts8, counts8, sortedU);

    transpose_all<<<576, 256, 0, stream>>>(W_var_emb, W_cls_emb, sv_W, sc_W,
                                           cp_Wl, cp_Wr, cn_Wl, cn_Wr, Wt);
    embed_ln<<<NN / 8, 128, 0, stream>>>(x_var, WtEv, ln_var_g, ln_var_b, var_pw, sv_b, F, C);
    embed_ln<<<NN / 8, 128, 0, stream>>>(x_cls, WtEc, ln_cls_g, ln_cls_b, cls_pw, sc_b, G, D);
    init_out<<<(2 * NN * 128 + 255) / 256, 256, 0, stream>>>(cp_b, cn_b, out0);

    // ---- self attention ----
    for (int side = 0; side < 2; ++side) {
        const float* h    = side ? D : C;
        float*       acc  = side ? G : F;
        const float* attl = side ? sc_al : sv_al;
        const float* attr = side ? sc_ar : sv_ar;
        const float* pw   = side ? cls_pw : var_pw;
        const float* Wts[2] = { side ? WtSc0 : WtSv0, side ? WtSc1 : WtSv1 };
        for (int p = 0; p < 2; ++p) {
            int seg = side * 2 + p;
            gemm_dots<<<NN / 8, 128, 0, stream>>>(h, Wts[p], attl + p * 512, attr + p * 512,
                                                  B1, dl, dr);
            agg_sorted<<<NN, 128, 0, stream>>>(starts8 + seg * NN, counts8 + seg * NN,
                                               sortedU + (size_t)seg * EE,
                                               dl, dr, B1, pw, p, 1, acc);
        }
    }

    // ---- cross attention ----
    for (int sign = 0; sign < 2; ++sign) {
        const float* Wl   = sign ? WtCnl : WtCpl;
        const float* Wr   = sign ? WtCnr : WtCpr;
        const float* attl = sign ? cn_al : cp_al;
        const float* attr = sign ? cn_ar : cp_ar;
        int segV = 4 + sign * 2;       // var-direction CSR
        int segC = 5 + sign * 2;       // cls-direction CSR
        gemm_dots<<<NN / 8, 128, 0, stream>>>(F, Wl, attl, attr, B1, dl, dr);    // xl: dl=al, dr=ar_
        gemm_dots<<<NN / 8, 128, 0, stream>>>(G, Wr, attl, attr, B2, dl2, dr2);  // xr: dl2=al_, dr2=ar
        // var direction: dst=v, a_dst=al(dl), a_src=ar(dr2), feats=xr(B2) -> out0
        agg_sorted<<<NN, 128, 0, stream>>>(starts8 + segV * NN, counts8 + segV * NN,
                                           sortedU + (size_t)segV * EE,
                                           dl, dr2, B2, nullptr, 0, 0, out0);
        // cls direction: dst=c, a_dst=al_(dl2), a_src=ar_(dr), feats=xl(B1) -> out1
        agg_sorted<<<NN, 128, 0, stream>>>(starts8 + segC * NN, counts8 + segC * NN,
                                           sortedU + (size_t)segC * EE,
                                           dl2, dr, B1, nullptr, 0, 0, out1);
    }
}

// Round 5
// 1057.934 us; speedup vs baseline: 3.9810x; 1.4925x over previous
//
#include <hip/hip_runtime.h>
#include <hip/hip_bf16.h>

#define NN 50000
#define EE 640000
#define NEG 0.2f
#define CAP 128          // per-segment LDS cache; degree ~ Poisson(12.8), P(k>128) ~ 0

#define BSH 7                          // 128 dsts per bucket
#define NBKT 391                       // ceil(NN/128)
#define CHUNKA 8192
#define PA_B 79                        // ceil(EE/CHUNKA)

struct Ptr8 { const int* p[8]; };
struct MArgs { const float* w[8]; const float* al[8]; const float* ar[8]; };

typedef __attribute__((ext_vector_type(8))) short short8;
typedef __attribute__((ext_vector_type(4))) float floatx4;

__device__ __forceinline__ unsigned short f2bf(float x) {
    unsigned b = __float_as_uint(x);
    b = b + 0x7fffu + ((b >> 16) & 1u);   // RNE
    return (unsigned short)(b >> 16);
}

// ---------------- transpose embedding weights ----------------
__global__ void transpose_emb(const float* __restrict__ wev, const float* __restrict__ wec,
                              float* __restrict__ out)
{
    int i = blockIdx.x * 256 + threadIdx.x;
    if (i < 8192) { out[i] = wev[(i & 127) * 64 + (i >> 7)]; return; }
    if (i < 16384) { int j = i - 8192; out[i] = wec[(j & 127) * 64 + (j >> 7)]; }
}

// ---------------- M[p] = W_p^T @ [attL | attR]  (128x8 per projection) ----------------
__global__ void make_M(MArgs a, float* __restrict__ Mbuf)
{
    int b = blockIdx.x;
    const float* W  = a.w[b];
    const float* AL = a.al[b];
    const float* AR = a.ar[b];
    for (int e = threadIdx.x; e < 1024; e += 256) {
        int k = e >> 3, h = e & 7;
        const float* att = (h < 4) ? AL : AR;
        int hh = h & 3;
        float s = 0.f;
        for (int c = 0; c < 128; c++) s += W[c * 128 + k] * att[c * 4 + hh];
        Mbuf[b * 1024 + e] = s;
    }
}

// ---------------- embedding GEMM + LayerNorm ----------------
__global__ void embed_ln(const float* __restrict__ x, const float* __restrict__ Wt,
                         const float* __restrict__ g, const float* __restrict__ b,
                         const float* __restrict__ pw, const float* __restrict__ sb,
                         float* __restrict__ F, float* __restrict__ C)
{
    __shared__ float lx[8][64];
    __shared__ float red[2][8][2];
    int c = threadIdx.x;
    int n0 = blockIdx.x * 8;
    for (int t = c; t < 8 * 64; t += 128) {
        lx[t >> 6][t & 63] = x[(size_t)(n0 + (t >> 6)) * 64 + (t & 63)];
    }
    __syncthreads();
    float acc[8];
#pragma unroll
    for (int m = 0; m < 8; m++) acc[m] = 0.f;
    for (int k = 0; k < 64; k++) {
        float w = Wt[k * 128 + c];
#pragma unroll
        for (int m = 0; m < 8; m++) acc[m] += lx[m][k] * w;
    }
    int lane = c & 63, wv = c >> 6;
#pragma unroll
    for (int m = 0; m < 8; m++) {
        float s1 = acc[m], s2 = acc[m] * acc[m];
        for (int off = 32; off; off >>= 1) { s1 += __shfl_xor(s1, off); s2 += __shfl_xor(s2, off); }
        if (lane == 0) { red[wv][m][0] = s1; red[wv][m][1] = s2; }
    }
    __syncthreads();
    float biassum = pw[0] * sb[c] + pw[1] * sb[128 + c];
    float gg = g[c], bb = b[c];
#pragma unroll
    for (int m = 0; m < 8; m++) {
        float s1 = red[0][m][0] + red[1][m][0];
        float s2 = red[0][m][1] + red[1][m][1];
        float mu  = s1 * (1.f / 128.f);
        float var = s2 * (1.f / 128.f) - mu * mu;
        float inv = rsqrtf(var + 1e-5f);
        float v = acc[m];
        size_t idx = (size_t)(n0 + m) * 128 + c;
        F[idx] = v + biassum;
        C[idx] = (v - mu) * inv * gg + bb;
    }
}

// ---------------- MFMA projection: out_bf = bf16(in @ W^T), dl/dr = in @ M ----------------
// Block: 256 threads = 4 waves, 16 rows/wave. W staged in LDS (bf16, XOR-swizzled 16B chunks).
__global__ __launch_bounds__(256) void mfma_proj(
    const float* __restrict__ in,        // [NN][128] fp32
    const float* __restrict__ W,         // [128][128] fp32, [out][in]
    const float* __restrict__ M,         // [128][8] fp32
    unsigned short* __restrict__ out_bf, // [NN][128] bf16
    float4* __restrict__ dl4, float4* __restrict__ dr4)
{
    __shared__ unsigned short WL[16384];  // 128 rows x 16 chunks x 8 bf16, swizzled
    __shared__ float ML[1024];            // 128 x 8

    int t = threadIdx.x;
    // stage W -> WL bf16; chunk (n, c16) stored at chunk slot (c16 ^ (n&15))
    for (int i = t; i < 2048; i += 256) {
        int n = i >> 4, c16 = i & 15;
        const float* src = W + n * 128 + c16 * 8;
        short8 v;
#pragma unroll
        for (int j = 0; j < 8; j++) v[j] = (short)f2bf(src[j]);
        *(short8*)&WL[(n * 16 + (c16 ^ (n & 15))) * 8] = v;
    }
    for (int i = t; i < 1024; i += 256) ML[i] = M[i];
    __syncthreads();

    int w = t >> 6, lane = t & 63;
    int ln = lane & 15, quad = lane >> 4;
    int rbase = blockIdx.x * 64 + w * 16;
    int row = rbase + ln;
    int arow = (row < NN) ? row : (NN - 1);

    // A-frags (4 K-chunks of 32) + fp32 dot partials against M
    short8 afrag[4];
    float p[8];
#pragma unroll
    for (int h = 0; h < 8; h++) p[h] = 0.f;
#pragma unroll
    for (int kc = 0; kc < 4; kc++) {
        int k0 = kc * 32 + quad * 8;
        const float* ap = in + (size_t)arow * 128 + k0;
        float av[8];
#pragma unroll
        for (int j = 0; j < 8; j++) av[j] = ap[j];
#pragma unroll
        for (int j = 0; j < 8; j++) {
            afrag[kc][j] = (short)f2bf(av[j]);
            const float* mrow = &ML[(k0 + j) * 8];
#pragma unroll
            for (int h = 0; h < 8; h++) p[h] += av[j] * mrow[h];
        }
    }
#pragma unroll
    for (int h = 0; h < 8; h++) {
        p[h] += __shfl_xor(p[h], 16);
        p[h] += __shfl_xor(p[h], 32);
    }
    if (quad == 0 && row < NN) {
        dl4[row] = make_float4(p[0], p[1], p[2], p[3]);
        dr4[row] = make_float4(p[4], p[5], p[6], p[7]);
    }

    // MFMA over 8 column tiles
#pragma unroll
    for (int ct = 0; ct < 8; ct++) {
        floatx4 acc = {0.f, 0.f, 0.f, 0.f};
#pragma unroll
        for (int kc = 0; kc < 4; kc++) {
            int c16 = kc * 4 + quad;
            int n = ct * 16 + ln;
            short8 bfr = *(const short8*)&WL[(n * 16 + (c16 ^ ln)) * 8];
            acc = __builtin_amdgcn_mfma_f32_16x16x32_bf16(afrag[kc], bfr, acc, 0, 0, 0);
        }
#pragma unroll
        for (int r = 0; r < 4; r++) {
            int rr = rbase + quad * 4 + r;
            if (rr < NN) out_bf[(size_t)rr * 128 + ct * 16 + ln] = f2bf(acc[r]);
        }
    }
}

// ---------------- init output with biases ----------------
__global__ void init_out(const float* __restrict__ b0, const float* __restrict__ b1,
                         float* __restrict__ out)
{
    int i = blockIdx.x * 256 + threadIdx.x;
    if (i < 2 * NN * 128) out[i] = b0[i & 127] + b1[i & 127];
}

// ================= two-level bucket sort (8 edge lists) =================
__global__ void zero_bcnt(int* __restrict__ p)
{
    int i = blockIdx.x * 256 + threadIdx.x;
    if (i < 8 * NBKT) p[i] = 0;
}

__global__ void bucket_count(Ptr8 dst, int* __restrict__ bcnt)
{
    __shared__ int h[NBKT];
    int l = blockIdx.x / PA_B, cb = blockIdx.x % PA_B;
    const int* dp = dst.p[l];
    for (int i = threadIdx.x; i < NBKT; i += 256) h[i] = 0;
    __syncthreads();
    int e0 = cb * CHUNKA;
    for (int i = threadIdx.x; i < CHUNKA; i += 256) {
        int e = e0 + i;
        if (e < EE) atomicAdd(&h[dp[e] >> BSH], 1);
    }
    __syncthreads();
    for (int i = threadIdx.x; i < NBKT; i += 256)
        if (h[i]) atomicAdd(&bcnt[l * NBKT + i], h[i]);
}

__global__ void bucket_scan(const int* __restrict__ bcnt, int* __restrict__ bstart,
                            int* __restrict__ bcur)
{
    __shared__ int sh[NBKT];
    int l = blockIdx.x;
    for (int i = threadIdx.x; i < NBKT; i += 256) sh[i] = bcnt[l * NBKT + i];
    __syncthreads();
    if (threadIdx.x == 0) {
        int acc = 0;
        for (int i = 0; i < NBKT; i++) { int t = sh[i]; sh[i] = acc; acc += t; }
    }
    __syncthreads();
    for (int i = threadIdx.x; i < NBKT; i += 256) {
        bstart[l * (NBKT + 1) + i] = sh[i];
        bcur[l * NBKT + i] = sh[i];
    }
    if (threadIdx.x == 0) bstart[l * (NBKT + 1) + NBKT] = EE;
}

__global__ void bucket_place(Ptr8 src, Ptr8 dst, int* __restrict__ bcur,
                             unsigned* __restrict__ recs)
{
    __shared__ int h[NBKT];
    __shared__ int base[NBKT];
    int l = blockIdx.x / PA_B, cb = blockIdx.x % PA_B;
    const int* sp = src.p[l];
    const int* dp = dst.p[l];
    for (int i = threadIdx.x; i < NBKT; i += 256) h[i] = 0;
    __syncthreads();
    int e0 = cb * CHUNKA;
    for (int i = threadIdx.x; i < CHUNKA; i += 256) {
        int e = e0 + i;
        if (e < EE) atomicAdd(&h[dp[e] >> BSH], 1);
    }
    __syncthreads();
    for (int i = threadIdx.x; i < NBKT; i += 256) {
        int c = h[i];
        base[i] = c ? atomicAdd(&bcur[l * NBKT + i], c) : 0;
        h[i] = 0;
    }
    __syncthreads();
    unsigned* rl = recs + (size_t)l * EE;
    for (int i = threadIdx.x; i < CHUNKA; i += 256) {
        int e = e0 + i;
        if (e >= EE) continue;
        int d = dp[e];
        int b = d >> BSH;
        int pos = base[b] + atomicAdd(&h[b], 1);
        rl[pos] = ((unsigned)sp[e] << 16) | (unsigned)d;
    }
}

__global__ void bucket_final(const unsigned* __restrict__ recs,
                             const int* __restrict__ bstart,
                             int* __restrict__ starts8, int* __restrict__ counts8,
                             unsigned short* __restrict__ sortedU)
{
    __shared__ int cnt[128];
    __shared__ int cur[128];
    int l = blockIdx.x / NBKT, b = blockIdx.x % NBKT;
    int d0 = b << BSH;
    int nd = min(128, NN - d0);
    int ebase = bstart[l * (NBKT + 1) + b];
    int ecnt  = bstart[l * (NBKT + 1) + b + 1] - ebase;
    const unsigned* rp = recs + (size_t)l * EE + ebase;
    int t = threadIdx.x;
    if (t < 128) cnt[t] = 0;
    __syncthreads();
    for (int i = t; i < ecnt; i += 256)
        atomicAdd(&cnt[(rp[i] & 0xffffu) - d0], 1);
    __syncthreads();
    if (t == 0) {
        int acc = 0;
        for (int i = 0; i < 128; i++) { int c = cnt[i]; cur[i] = acc; acc += c; }
    }
    __syncthreads();
    if (t < nd) {
        starts8[l * NN + d0 + t] = ebase + cur[t];
        counts8[l * NN + d0 + t] = cnt[t];
    }
    __syncthreads();
    unsigned short* so = sortedU + (size_t)l * EE + ebase;
    for (int i = t; i < ecnt; i += 256) {
        unsigned r = rp[i];
        int dloc = (int)(r & 0xffffu) - d0;
        int pos = atomicAdd(&cur[dloc], 1);
        so[pos] = (unsigned short)(r >> 16);
    }
}

// ---------------- fused segment softmax + bf16 gather aggregation ----------------
__global__ __launch_bounds__(128) void agg_sorted(
    const int* __restrict__ starts, const int* __restrict__ counts,
    const unsigned short* __restrict__ sortedSrc,
    const float* __restrict__ a_dst, const float* __restrict__ a_src,
    const unsigned short* __restrict__ feats,   // bf16 bits [NN][128]
    const float* __restrict__ pw, int pwi, int hasLoop,
    float* __restrict__ acc)
{
    __shared__ float4 exSh[CAP];
    __shared__ int    sSh[CAP];
    __shared__ float  wSh[CAP];
    __shared__ float  red[2][4];
    __shared__ float  denSh[4];
    __shared__ float  cmb[2][64][2];

    int d = blockIdx.x;
    int t = threadIdx.x;
    int base = starts[d];
    int k = counts[d];
    int kTot = k + hasLoop;

    float4 ad = *(const float4*)(a_dst + (size_t)d * 4);
    float p0 = 0.f, p1 = 0.f, p2 = 0.f, p3 = 0.f;
    for (int i = t; i < kTot; i += 128) {
        int s = (i < k) ? (int)sortedSrc[base + i] : d;
        float4 as = *(const float4*)(a_src + (size_t)s * 4);
        float v0 = ad.x + as.x, v1 = ad.y + as.y, v2 = ad.z + as.z, v3 = ad.w + as.w;
        v0 = v0 > 0.f ? v0 : NEG * v0;
        v1 = v1 > 0.f ? v1 : NEG * v1;
        v2 = v2 > 0.f ? v2 : NEG * v2;
        v3 = v3 > 0.f ? v3 : NEG * v3;
        float e0 = __expf(v0), e1 = __expf(v1), e2 = __expf(v2), e3 = __expf(v3);
        if (i < CAP) { exSh[i] = make_float4(e0, e1, e2, e3); sSh[i] = s; }
        p0 += e0; p1 += e1; p2 += e2; p3 += e3;
    }
    for (int off = 32; off; off >>= 1) {
        p0 += __shfl_xor(p0, off); p1 += __shfl_xor(p1, off);
        p2 += __shfl_xor(p2, off); p3 += __shfl_xor(p3, off);
    }
    int lane = t & 63, half = t >> 6;
    if (lane == 0) { red[half][0] = p0; red[half][1] = p1; red[half][2] = p2; red[half][3] = p3; }
    __syncthreads();
    if (t < 4) denSh[t] = red[0][t] + red[1][t];
    __syncthreads();

    float scale = 0.25f * (pw ? pw[pwi] : 1.0f);
    float d0 = denSh[0] + 1e-16f, d1 = denSh[1] + 1e-16f;
    float d2 = denSh[2] + 1e-16f, d3 = denSh[3] + 1e-16f;
    if (t < CAP && t < kTot) {
        float4 ex = exSh[t];
        wSh[t] = scale * (ex.x / d0 + ex.y / d1 + ex.z / d2 + ex.w / d3);
    }
    __syncthreads();

    float a0 = 0.f, a1 = 0.f;
    for (int j = half; j < kTot; j += 2) {
        float w; int s;
        if (j < CAP) { w = wSh[j]; s = sSh[j]; }
        else {
            s = (j < k) ? (int)sortedSrc[base + j] : d;
            float4 as = *(const float4*)(a_src + (size_t)s * 4);
            float v0 = ad.x + as.x, v1 = ad.y + as.y, v2 = ad.z + as.z, v3 = ad.w + as.w;
            v0 = v0 > 0.f ? v0 : NEG * v0;
            v1 = v1 > 0.f ? v1 : NEG * v1;
            v2 = v2 > 0.f ? v2 : NEG * v2;
            v3 = v3 > 0.f ? v3 : NEG * v3;
            w = scale * (__expf(v0) / d0 + __expf(v1) / d1 + __expf(v2) / d2 + __expf(v3) / d3);
        }
        unsigned v = *(const unsigned*)(feats + (size_t)s * 128 + 2 * lane);
        float f0 = __uint_as_float(v << 16);
        float f1 = __uint_as_float(v & 0xffff0000u);
        a0 += w * f0; a1 += w * f1;
    }
    cmb[half][lane][0] = a0; cmb[half][lane][1] = a1;
    __syncthreads();
    if (t < 64) {
        size_t o = (size_t)d * 128 + 2 * t;
        float2 prev = *(const float2*)(acc + o);
        prev.x += cmb[0][t][0] + cmb[1][t][0];
        prev.y += cmb[0][t][1] + cmb[1][t][1];
        *(float2*)(acc + o) = prev;
    }
}

extern "C" void kernel_launch(void* const* d_in, const int* in_sizes, int n_in,
                              void* d_out, int out_size, void* d_ws, size_t ws_size,
                              hipStream_t stream)
{
    const float* x_var   = (const float*)d_in[0];
    const float* x_cls   = (const float*)d_in[1];
    const int*   mp_var  = (const int*)d_in[2];
    const int*   mp_cls  = (const int*)d_in[3];
    const int*   adj_pos = (const int*)d_in[4];
    const int*   adj_neg = (const int*)d_in[5];
    const float* W_var_emb = (const float*)d_in[6];
    const float* W_cls_emb = (const float*)d_in[7];
    const float* ln_var_g = (const float*)d_in[8];
    const float* ln_var_b = (const float*)d_in[9];
    const float* ln_cls_g = (const float*)d_in[10];
    const float* ln_cls_b = (const float*)d_in[11];
    const float* var_pw = (const float*)d_in[12];
    const float* cls_pw = (const float*)d_in[13];
    const float* sv_W  = (const float*)d_in[14];
    const float* sv_al = (const float*)d_in[15];
    const float* sv_ar = (const float*)d_in[16];
    const float* sv_b  = (const float*)d_in[17];
    const float* sc_W  = (const float*)d_in[18];
    const float* sc_al = (const float*)d_in[19];
    const float* sc_ar = (const float*)d_in[20];
    const float* sc_b  = (const float*)d_in[21];
    const float* cp_Wl = (const float*)d_in[22];
    const float* cp_Wr = (const float*)d_in[23];
    const float* cp_al = (const float*)d_in[24];
    const float* cp_ar = (const float*)d_in[25];
    const float* cp_b  = (const float*)d_in[26];
    const float* cn_Wl = (const float*)d_in[27];
    const float* cn_Wr = (const float*)d_in[28];
    const float* cn_al = (const float*)d_in[29];
    const float* cn_ar = (const float*)d_in[30];
    const float* cn_b  = (const float*)d_in[31];

    float* out0 = (float*)d_out;
    float* out1 = out0 + (size_t)NN * 128;

    float* ws = (float*)d_ws;
    size_t off = 0;
    auto alloc = [&](size_t n) { float* p = ws + off; off += n; return p; };
    float* Wt   = alloc(16384);             // embed weights transposed
    float* Mbuf = alloc(8 * 1024);          // 8 projections x [128][8]
    float* F   = alloc((size_t)NN * 128);
    float* G   = alloc((size_t)NN * 128);
    float* C   = alloc((size_t)NN * 128);   // hv
    float* D   = alloc((size_t)NN * 128);   // hc
    unsigned short* B1 = (unsigned short*)alloc((size_t)NN * 64);  // bf16 [NN][128]
    unsigned short* B2 = (unsigned short*)alloc((size_t)NN * 64);
    float* dl   = alloc(NN * 4);
    float* dr   = alloc(NN * 4);
    float* dl2  = alloc(NN * 4);
    float* dr2  = alloc(NN * 4);
    int* counts8 = (int*)alloc(8 * NN);
    int* starts8 = (int*)alloc(8 * NN);
    int* bcnt    = (int*)alloc(8 * NBKT);
    int* bstart  = (int*)alloc(8 * (NBKT + 1));
    int* bcur    = (int*)alloc(8 * NBKT);
    unsigned* recs = (unsigned*)alloc((size_t)8 * EE);
    unsigned short* sortedU = (unsigned short*)alloc((size_t)4 * EE);

    const float* WtEv = Wt;
    const float* WtEc = Wt + 8192;

    // edge-list table: 0..3 = self (mp_var p0,p1, mp_cls p0,p1); 4 = pos var-dir;
    // 5 = pos cls-dir; 6 = neg var-dir; 7 = neg cls-dir
    Ptr8 srcP, dstP;
    srcP.p[0] = mp_var;            dstP.p[0] = mp_var + EE;
    srcP.p[1] = mp_var + 2 * EE;   dstP.p[1] = mp_var + 3 * EE;
    srcP.p[2] = mp_cls;            dstP.p[2] = mp_cls + EE;
    srcP.p[3] = mp_cls + 2 * EE;   dstP.p[3] = mp_cls + 3 * EE;
    srcP.p[4] = adj_pos;           dstP.p[4] = adj_pos + EE;
    srcP.p[5] = adj_pos + EE;      dstP.p[5] = adj_pos;
    srcP.p[6] = adj_neg;           dstP.p[6] = adj_neg + EE;
    srcP.p[7] = adj_neg + EE;      dstP.p[7] = adj_neg;

    // projection table (W, attL, attR) for make_M / mfma_proj
    MArgs ma;
    ma.w[0] = sv_W;           ma.al[0] = sv_al;        ma.ar[0] = sv_ar;
    ma.w[1] = sv_W + 16384;   ma.al[1] = sv_al + 512;  ma.ar[1] = sv_ar + 512;
    ma.w[2] = sc_W;           ma.al[2] = sc_al;        ma.ar[2] = sc_ar;
    ma.w[3] = sc_W + 16384;   ma.al[3] = sc_al + 512;  ma.ar[3] = sc_ar + 512;
    ma.w[4] = cp_Wl;          ma.al[4] = cp_al;        ma.ar[4] = cp_ar;
    ma.w[5] = cp_Wr;          ma.al[5] = cp_al;        ma.ar[5] = cp_ar;
    ma.w[6] = cn_Wl;          ma.al[6] = cn_al;        ma.ar[6] = cn_ar;
    ma.w[7] = cn_Wr;          ma.al[7] = cn_al;        ma.ar[7] = cn_ar;

    // ---- two-level bucket sort of all 8 edge lists ----
    zero_bcnt<<<(8 * NBKT + 255) / 256, 256, 0, stream>>>(bcnt);
    bucket_count<<<8 * PA_B, 256, 0, stream>>>(dstP, bcnt);
    bucket_scan<<<8, 256, 0, stream>>>(bcnt, bstart, bcur);
    bucket_place<<<8 * PA_B, 256, 0, stream>>>(srcP, dstP, bcur, recs);
    bucket_final<<<8 * NBKT, 256, 0, stream>>>(recs, bstart, starts8, counts8, sortedU);

    transpose_emb<<<64, 256, 0, stream>>>(W_var_emb, W_cls_emb, Wt);
    make_M<<<8, 256, 0, stream>>>(ma, Mbuf);
    embed_ln<<<NN / 8, 128, 0, stream>>>(x_var, WtEv, ln_var_g, ln_var_b, var_pw, sv_b, F, C);
    embed_ln<<<NN / 8, 128, 0, stream>>>(x_cls, WtEc, ln_cls_g, ln_cls_b, cls_pw, sc_b, G, D);
    init_out<<<(2 * NN * 128 + 255) / 256, 256, 0, stream>>>(cp_b, cn_b, out0);

    const int PB = (NN + 63) / 64;   // 782 blocks for mfma_proj

    // ---- self attention ----
    for (int side = 0; side < 2; ++side) {
        const float* h   = side ? D : C;
        float*       acc = side ? G : F;
        const float* pw  = side ? cls_pw : var_pw;
        for (int p = 0; p < 2; ++p) {
            int seg = side * 2 + p;
            mfma_proj<<<PB, 256, 0, stream>>>(h, ma.w[seg], Mbuf + seg * 1024,
                                              B1, (float4*)dl, (float4*)dr);
            agg_sorted<<<NN, 128, 0, stream>>>(starts8 + seg * NN, counts8 + seg * NN,
                                               sortedU + (size_t)seg * EE,
                                               dl, dr, B1, pw, p, 1, acc);
        }
    }

    // ---- cross attention ----
    for (int sign = 0; sign < 2; ++sign) {
        int pl = 4 + sign * 2;         // xl projection (cp/cn _Wl)
        int pr = 5 + sign * 2;         // xr projection (cp/cn _Wr)
        int segV = 4 + sign * 2;       // var-direction CSR
        int segC = 5 + sign * 2;       // cls-direction CSR
        mfma_proj<<<PB, 256, 0, stream>>>(F, ma.w[pl], Mbuf + pl * 1024,
                                          B1, (float4*)dl, (float4*)dr);    // dl=al, dr=ar_
        mfma_proj<<<PB, 256, 0, stream>>>(G, ma.w[pr], Mbuf + pr * 1024,
                                          B2, (float4*)dl2, (float4*)dr2);  // dl2=al_, dr2=ar
        // var direction: dst=v, a_dst=al(dl), a_src=ar(dr2), feats=xr(B2) -> out0
        agg_sorted<<<NN, 128, 0, stream>>>(starts8 + segV * NN, counts8 + segV * NN,
                                           sortedU + (size_t)segV * EE,
                                           dl, dr2, B2, nullptr, 0, 0, out0);
        // cls direction: dst=c, a_dst=al_(dl2), a_src=ar_(dr), feats=xl(B1) -> out1
        agg_sorted<<<NN, 128, 0, stream>>>(starts8 + segC * NN, counts8 + segC * NN,
                                           sortedU + (size_t)segC * EE,
                                           dl2, dr, B1, nullptr, 0, 0, out1);
    }
}

// Round 6
// 948.297 us; speedup vs baseline: 4.4412x; 1.1156x over previous
//
#include <hip/hip_runtime.h>
#include <hip/hip_bf16.h>

#define NN 50000
#define EE 640000
#define NEG 0.2f
#define CAP 128          // per-segment cache; degree ~ Poisson(12.8), P(k>128) ~ 0

#define BSH 9                          // 512 dsts per bucket
#define NBKT 98                        // ceil(NN/512)
#define FCAP 7168                      // LDS record stage in bucket_final
#define CHUNKA 8192
#define PA_B 79                        // ceil(EE/CHUNKA)

struct Ptr8 { const int* p[8]; };
struct MArgs { const float* w[8]; const float* al[8]; const float* ar[8]; };

typedef __attribute__((ext_vector_type(8))) short short8;
typedef __attribute__((ext_vector_type(8))) unsigned short ushort8;
typedef __attribute__((ext_vector_type(4))) float floatx4;

__device__ __forceinline__ unsigned short f2bf(float x) {
    unsigned b = __float_as_uint(x);
    b = b + 0x7fffu + ((b >> 16) & 1u);   // RNE
    return (unsigned short)(b >> 16);
}

// ---------------- transpose embedding weights ----------------
__global__ void transpose_emb(const float* __restrict__ wev, const float* __restrict__ wec,
                              float* __restrict__ out)
{
    int i = blockIdx.x * 256 + threadIdx.x;
    if (i < 8192) { out[i] = wev[(i & 127) * 64 + (i >> 7)]; return; }
    if (i < 16384) { int j = i - 8192; out[i] = wec[(j & 127) * 64 + (j >> 7)]; }
}

// ---------------- M[p] = W_p^T @ [attL | attR]  (128x8 per projection) ----------------
__global__ void make_M(MArgs a, float* __restrict__ Mbuf)
{
    int b = blockIdx.x;
    const float* W  = a.w[b];
    const float* AL = a.al[b];
    const float* AR = a.ar[b];
    for (int e = threadIdx.x; e < 1024; e += 256) {
        int k = e >> 3, h = e & 7;
        const float* att = (h < 4) ? AL : AR;
        int hh = h & 3;
        float s = 0.f;
        for (int c = 0; c < 128; c++) s += W[c * 128 + k] * att[c * 4 + hh];
        Mbuf[b * 1024 + e] = s;
    }
}

// ---------------- embedding GEMM + LayerNorm ----------------
__global__ void embed_ln(const float* __restrict__ x, const float* __restrict__ Wt,
                         const float* __restrict__ g, const float* __restrict__ b,
                         const float* __restrict__ pw, const float* __restrict__ sb,
                         float* __restrict__ F, float* __restrict__ C)
{
    __shared__ float lx[8][64];
    __shared__ float red[2][8][2];
    int c = threadIdx.x;
    int n0 = blockIdx.x * 8;
    for (int t = c; t < 8 * 64; t += 128) {
        lx[t >> 6][t & 63] = x[(size_t)(n0 + (t >> 6)) * 64 + (t & 63)];
    }
    __syncthreads();
    float acc[8];
#pragma unroll
    for (int m = 0; m < 8; m++) acc[m] = 0.f;
    for (int k = 0; k < 64; k++) {
        float w = Wt[k * 128 + c];
#pragma unroll
        for (int m = 0; m < 8; m++) acc[m] += lx[m][k] * w;
    }
    int lane = c & 63, wv = c >> 6;
#pragma unroll
    for (int m = 0; m < 8; m++) {
        float s1 = acc[m], s2 = acc[m] * acc[m];
        for (int off = 32; off; off >>= 1) { s1 += __shfl_xor(s1, off); s2 += __shfl_xor(s2, off); }
        if (lane == 0) { red[wv][m][0] = s1; red[wv][m][1] = s2; }
    }
    __syncthreads();
    float biassum = pw[0] * sb[c] + pw[1] * sb[128 + c];
    float gg = g[c], bb = b[c];
#pragma unroll
    for (int m = 0; m < 8; m++) {
        float s1 = red[0][m][0] + red[1][m][0];
        float s2 = red[0][m][1] + red[1][m][1];
        float mu  = s1 * (1.f / 128.f);
        float var = s2 * (1.f / 128.f) - mu * mu;
        float inv = rsqrtf(var + 1e-5f);
        float v = acc[m];
        size_t idx = (size_t)(n0 + m) * 128 + c;
        F[idx] = v + biassum;
        C[idx] = (v - mu) * inv * gg + bb;
    }
}

// ---------------- MFMA projection: out_bf = bf16(in @ W^T), dl/dr = in @ M ----------------
__global__ __launch_bounds__(256) void mfma_proj(
    const float* __restrict__ in,        // [NN][128] fp32
    const float* __restrict__ W,         // [128][128] fp32, [out][in]
    const float* __restrict__ M,         // [128][8] fp32
    unsigned short* __restrict__ out_bf, // [NN][128] bf16
    float4* __restrict__ dl4, float4* __restrict__ dr4)
{
    __shared__ unsigned short WL[16384];  // 128 rows x 16 chunks x 8 bf16, swizzled
    __shared__ float ML[1024];            // 128 x 8

    int t = threadIdx.x;
    for (int i = t; i < 2048; i += 256) {
        int n = i >> 4, c16 = i & 15;
        const float* src = W + n * 128 + c16 * 8;
        short8 v;
#pragma unroll
        for (int j = 0; j < 8; j++) v[j] = (short)f2bf(src[j]);
        *(short8*)&WL[(n * 16 + (c16 ^ (n & 15))) * 8] = v;
    }
    for (int i = t; i < 1024; i += 256) ML[i] = M[i];
    __syncthreads();

    int w = t >> 6, lane = t & 63;
    int ln = lane & 15, quad = lane >> 4;
    int rbase = blockIdx.x * 64 + w * 16;
    int row = rbase + ln;
    int arow = (row < NN) ? row : (NN - 1);

    short8 afrag[4];
    float p[8];
#pragma unroll
    for (int h = 0; h < 8; h++) p[h] = 0.f;
#pragma unroll
    for (int kc = 0; kc < 4; kc++) {
        int k0 = kc * 32 + quad * 8;
        const float* ap = in + (size_t)arow * 128 + k0;
        float av[8];
#pragma unroll
        for (int j = 0; j < 8; j++) av[j] = ap[j];
#pragma unroll
        for (int j = 0; j < 8; j++) {
            afrag[kc][j] = (short)f2bf(av[j]);
            const float* mrow = &ML[(k0 + j) * 8];
#pragma unroll
            for (int h = 0; h < 8; h++) p[h] += av[j] * mrow[h];
        }
    }
#pragma unroll
    for (int h = 0; h < 8; h++) {
        p[h] += __shfl_xor(p[h], 16);
        p[h] += __shfl_xor(p[h], 32);
    }
    if (quad == 0 && row < NN) {
        dl4[row] = make_float4(p[0], p[1], p[2], p[3]);
        dr4[row] = make_float4(p[4], p[5], p[6], p[7]);
    }

#pragma unroll
    for (int ct = 0; ct < 8; ct++) {
        floatx4 acc = {0.f, 0.f, 0.f, 0.f};
#pragma unroll
        for (int kc = 0; kc < 4; kc++) {
            int c16 = kc * 4 + quad;
            int n = ct * 16 + ln;
            short8 bfr = *(const short8*)&WL[(n * 16 + (c16 ^ ln)) * 8];
            acc = __builtin_amdgcn_mfma_f32_16x16x32_bf16(afrag[kc], bfr, acc, 0, 0, 0);
        }
#pragma unroll
        for (int r = 0; r < 4; r++) {
            int rr = rbase + quad * 4 + r;
            if (rr < NN) out_bf[(size_t)rr * 128 + ct * 16 + ln] = f2bf(acc[r]);
        }
    }
}

// ---------------- init output with biases ----------------
__global__ void init_out(const float* __restrict__ b0, const float* __restrict__ b1,
                         float* __restrict__ out)
{
    int i = blockIdx.x * 256 + threadIdx.x;
    if (i < 2 * NN * 128) out[i] = b0[i & 127] + b1[i & 127];
}

// ================= two-level bucket sort (8 edge lists) =================
__global__ void zero_bcnt(int* __restrict__ p)
{
    int i = blockIdx.x * 256 + threadIdx.x;
    if (i < 8 * NBKT) p[i] = 0;
}

__global__ void bucket_count(Ptr8 dst, int* __restrict__ bcnt)
{
    __shared__ int h[NBKT];
    int l = blockIdx.x / PA_B, cb = blockIdx.x % PA_B;
    const int* dp = dst.p[l];
    for (int i = threadIdx.x; i < NBKT; i += 256) h[i] = 0;
    __syncthreads();
    int e0 = cb * CHUNKA;
    for (int i = threadIdx.x; i < CHUNKA; i += 256) {
        int e = e0 + i;
        if (e < EE) atomicAdd(&h[dp[e] >> BSH], 1);
    }
    __syncthreads();
    for (int i = threadIdx.x; i < NBKT; i += 256)
        if (h[i]) atomicAdd(&bcnt[l * NBKT + i], h[i]);
}

__global__ void bucket_scan(const int* __restrict__ bcnt, int* __restrict__ bstart,
                            int* __restrict__ bcur)
{
    __shared__ int sh[NBKT];
    int l = blockIdx.x;
    for (int i = threadIdx.x; i < NBKT; i += 256) sh[i] = bcnt[l * NBKT + i];
    __syncthreads();
    if (threadIdx.x == 0) {
        int acc = 0;
        for (int i = 0; i < NBKT; i++) { int t = sh[i]; sh[i] = acc; acc += t; }
    }
    __syncthreads();
    for (int i = threadIdx.x; i < NBKT; i += 256) {
        bstart[l * (NBKT + 1) + i] = sh[i];
        bcur[l * NBKT + i] = sh[i];
    }
    if (threadIdx.x == 0) bstart[l * (NBKT + 1) + NBKT] = EE;
}

__global__ void bucket_place(Ptr8 src, Ptr8 dst, int* __restrict__ bcur,
                             unsigned* __restrict__ recs)
{
    __shared__ int h[NBKT];
    __shared__ int base[NBKT];
    int l = blockIdx.x / PA_B, cb = blockIdx.x % PA_B;
    const int* sp = src.p[l];
    const int* dp = dst.p[l];
    for (int i = threadIdx.x; i < NBKT; i += 256) h[i] = 0;
    __syncthreads();
    int e0 = cb * CHUNKA;
    for (int i = threadIdx.x; i < CHUNKA; i += 256) {
        int e = e0 + i;
        if (e < EE) atomicAdd(&h[dp[e] >> BSH], 1);
    }
    __syncthreads();
    for (int i = threadIdx.x; i < NBKT; i += 256) {
        int c = h[i];
        base[i] = c ? atomicAdd(&bcur[l * NBKT + i], c) : 0;
        h[i] = 0;
    }
    __syncthreads();
    unsigned* rl = recs + (size_t)l * EE;
    for (int i = threadIdx.x; i < CHUNKA; i += 256) {
        int e = e0 + i;
        if (e >= EE) continue;
        int d = dp[e];
        int b = d >> BSH;
        int pos = base[b] + atomicAdd(&h[b], 1);
        rl[pos] = ((unsigned)sp[e] << 16) | (unsigned)d;
    }
}

// one block per 512-dst bucket: stage recs in LDS, parallel scan, exact placement
__global__ __launch_bounds__(256) void bucket_final(
    const unsigned* __restrict__ recs, const int* __restrict__ bstart,
    int* __restrict__ starts8, int* __restrict__ counts8,
    unsigned short* __restrict__ sortedU)
{
    __shared__ unsigned R[FCAP];
    __shared__ int cnt[512];
    __shared__ int cur[512];
    __shared__ int psum[256];
    int l = blockIdx.x / NBKT, b = blockIdx.x % NBKT;
    int d0 = b << BSH;
    int nd = min(512, NN - d0);
    int ebase = bstart[l * (NBKT + 1) + b];
    int ecnt  = bstart[l * (NBKT + 1) + b + 1] - ebase;
    const unsigned* rp = recs + (size_t)l * EE + ebase;
    int t = threadIdx.x;
    bool inLds = (ecnt <= FCAP);

    for (int i = t; i < 512; i += 256) cnt[i] = 0;
    __syncthreads();
    for (int i = t; i < ecnt; i += 256) {
        unsigned r = rp[i];
        if (inLds) R[i] = r;
        atomicAdd(&cnt[(r & 0xffffu) - d0], 1);
    }
    __syncthreads();
    // exclusive scan of cnt[512]: pairwise partials + 256-ladder
    int s0 = cnt[2 * t] + cnt[2 * t + 1];
    psum[t] = s0;
    __syncthreads();
    for (int off = 1; off < 256; off <<= 1) {
        int x = (t >= off) ? psum[t - off] : 0;
        __syncthreads();
        psum[t] += x;
        __syncthreads();
    }
    int excl = psum[t] - s0;
    cur[2 * t] = excl;
    cur[2 * t + 1] = excl + cnt[2 * t];
    __syncthreads();
    for (int i = t; i < nd; i += 256) {
        starts8[l * NN + d0 + i] = ebase + cur[i];
        counts8[l * NN + d0 + i] = cnt[i];
    }
    __syncthreads();
    unsigned short* so = sortedU + (size_t)l * EE + ebase;
    for (int i = t; i < ecnt; i += 256) {
        unsigned r = inLds ? R[i] : rp[i];
        int dloc = (int)(r & 0xffffu) - d0;
        int pos = atomicAdd(&cur[dloc], 1);
        so[pos] = (unsigned short)(r >> 16);
    }
}

// ---------------- fused segment softmax + wide bf16 gather aggregation ----------------
__global__ __launch_bounds__(128) void agg_sorted(
    const int* __restrict__ starts, const int* __restrict__ counts,
    const unsigned short* __restrict__ sortedSrc,
    const float* __restrict__ a_dst, const float* __restrict__ a_src,
    const unsigned short* __restrict__ feats,   // bf16 bits [NN][128]
    const float* __restrict__ pw, int pwi, int hasLoop,
    float* __restrict__ acc)
{
    __shared__ float4 exSh[CAP];
    __shared__ int    sSh[CAP + 8];
    __shared__ float  wSh[CAP + 8];
    __shared__ float  red[2][4];
    __shared__ float  denSh[4];
    __shared__ float  cmb2[2][128];

    int d = blockIdx.x;
    int t = threadIdx.x;
    int base = starts[d];
    int k = counts[d];
    int kTot = k + hasLoop;

    float4 ad = *(const float4*)(a_dst + (size_t)d * 4);
    float p0 = 0.f, p1 = 0.f, p2 = 0.f, p3 = 0.f;
    for (int i = t; i < kTot; i += 128) {
        int s = (i < k) ? (int)sortedSrc[base + i] : d;
        float4 as = *(const float4*)(a_src + (size_t)s * 4);
        float v0 = ad.x + as.x, v1 = ad.y + as.y, v2 = ad.z + as.z, v3 = ad.w + as.w;
        v0 = v0 > 0.f ? v0 : NEG * v0;
        v1 = v1 > 0.f ? v1 : NEG * v1;
        v2 = v2 > 0.f ? v2 : NEG * v2;
        v3 = v3 > 0.f ? v3 : NEG * v3;
        float e0 = __expf(v0), e1 = __expf(v1), e2 = __expf(v2), e3 = __expf(v3);
        if (i < CAP) { exSh[i] = make_float4(e0, e1, e2, e3); sSh[i] = s; }
        p0 += e0; p1 += e1; p2 += e2; p3 += e3;
    }
    for (int off = 32; off; off >>= 1) {
        p0 += __shfl_xor(p0, off); p1 += __shfl_xor(p1, off);
        p2 += __shfl_xor(p2, off); p3 += __shfl_xor(p3, off);
    }
    int lane = t & 63, half = t >> 6;
    if (lane == 0) { red[half][0] = p0; red[half][1] = p1; red[half][2] = p2; red[half][3] = p3; }
    __syncthreads();
    if (t < 4) denSh[t] = red[0][t] + red[1][t];
    __syncthreads();

    float scale = 0.25f * (pw ? pw[pwi] : 1.0f);
    float d0 = denSh[0] + 1e-16f, d1 = denSh[1] + 1e-16f;
    float d2 = denSh[2] + 1e-16f, d3 = denSh[3] + 1e-16f;

    if (kTot <= CAP) {
        // ---- main path: 4-edge-per-wave, 16B loads ----
        if (t < kTot) {
            float4 ex = exSh[t];
            wSh[t] = scale * (ex.x / d0 + ex.y / d1 + ex.z / d2 + ex.w / d3);
        }
        int nIter = (kTot + 7) >> 3;
        for (int i = kTot + t; i < nIter * 8; i += 128) { wSh[i] = 0.f; sSh[i] = 0; }
        __syncthreads();

        int g = lane >> 4, c8 = lane & 15;
        float a[8];
#pragma unroll
        for (int i = 0; i < 8; i++) a[i] = 0.f;
        for (int it = 0; it < nIter; ++it) {
            int j = it * 8 + half * 4 + g;
            float w = wSh[j];
            int s = sSh[j];
            ushort8 v = *(const ushort8*)(feats + (size_t)s * 128 + c8 * 8);
#pragma unroll
            for (int i = 0; i < 8; i++)
                a[i] += w * __uint_as_float((unsigned)(unsigned short)v[i] << 16);
        }
#pragma unroll
        for (int i = 0; i < 8; i++) {
            a[i] += __shfl_xor(a[i], 16);
            a[i] += __shfl_xor(a[i], 32);
        }
        if (lane < 16) {
#pragma unroll
            for (int i = 0; i < 8; i++) cmb2[half][lane * 8 + i] = a[i];
        }
        __syncthreads();
        acc[(size_t)d * 128 + t] += cmb2[0][t] + cmb2[1][t];
    } else {
        // ---- rare fallback: degree > CAP ----
        if (t < CAP) {
            float4 ex = exSh[t];
            wSh[t] = scale * (ex.x / d0 + ex.y / d1 + ex.z / d2 + ex.w / d3);
        }
        __syncthreads();
        float a0 = 0.f, a1 = 0.f;
        for (int j = half; j < kTot; j += 2) {
            float w; int s;
            if (j < CAP) { w = wSh[j]; s = sSh[j]; }
            else {
                s = (j < k) ? (int)sortedSrc[base + j] : d;
                float4 as = *(const float4*)(a_src + (size_t)s * 4);
                float v0 = ad.x + as.x, v1 = ad.y + as.y, v2 = ad.z + as.z, v3 = ad.w + as.w;
                v0 = v0 > 0.f ? v0 : NEG * v0;
                v1 = v1 > 0.f ? v1 : NEG * v1;
                v2 = v2 > 0.f ? v2 : NEG * v2;
                v3 = v3 > 0.f ? v3 : NEG * v3;
                w = scale * (__expf(v0) / d0 + __expf(v1) / d1 + __expf(v2) / d2 + __expf(v3) / d3);
            }
            unsigned v = *(const unsigned*)(feats + (size_t)s * 128 + 2 * lane);
            a0 += w * __uint_as_float(v << 16);
            a1 += w * __uint_as_float(v & 0xffff0000u);
        }
        cmb2[half][2 * lane] = a0;
        cmb2[half][2 * lane + 1] = a1;
        __syncthreads();
        acc[(size_t)d * 128 + t] += cmb2[0][t] + cmb2[1][t];
    }
}

extern "C" void kernel_launch(void* const* d_in, const int* in_sizes, int n_in,
                              void* d_out, int out_size, void* d_ws, size_t ws_size,
                              hipStream_t stream)
{
    const float* x_var   = (const float*)d_in[0];
    const float* x_cls   = (const float*)d_in[1];
    const int*   mp_var  = (const int*)d_in[2];
    const int*   mp_cls  = (const int*)d_in[3];
    const int*   adj_pos = (const int*)d_in[4];
    const int*   adj_neg = (const int*)d_in[5];
    const float* W_var_emb = (const float*)d_in[6];
    const float* W_cls_emb = (const float*)d_in[7];
    const float* ln_var_g = (const float*)d_in[8];
    const float* ln_var_b = (const float*)d_in[9];
    const float* ln_cls_g = (const float*)d_in[10];
    const float* ln_cls_b = (const float*)d_in[11];
    const float* var_pw = (const float*)d_in[12];
    const float* cls_pw = (const float*)d_in[13];
    const float* sv_W  = (const float*)d_in[14];
    const float* sv_al = (const float*)d_in[15];
    const float* sv_ar = (const float*)d_in[16];
    const float* sv_b  = (const float*)d_in[17];
    const float* sc_W  = (const float*)d_in[18];
    const float* sc_al = (const float*)d_in[19];
    const float* sc_ar = (const float*)d_in[20];
    const float* sc_b  = (const float*)d_in[21];
    const float* cp_Wl = (const float*)d_in[22];
    const float* cp_Wr = (const float*)d_in[23];
    const float* cp_al = (const float*)d_in[24];
    const float* cp_ar = (const float*)d_in[25];
    const float* cp_b  = (const float*)d_in[26];
    const float* cn_Wl = (const float*)d_in[27];
    const float* cn_Wr = (const float*)d_in[28];
    const float* cn_al = (const float*)d_in[29];
    const float* cn_ar = (const float*)d_in[30];
    const float* cn_b  = (const float*)d_in[31];

    float* out0 = (float*)d_out;
    float* out1 = out0 + (size_t)NN * 128;

    float* ws = (float*)d_ws;
    size_t off = 0;
    auto alloc = [&](size_t n) { float* p = ws + off; off += n; return p; };
    float* Wt   = alloc(16384);
    float* Mbuf = alloc(8 * 1024);
    float* F   = alloc((size_t)NN * 128);
    float* G   = alloc((size_t)NN * 128);
    float* C   = alloc((size_t)NN * 128);   // hv
    float* D   = alloc((size_t)NN * 128);   // hc
    unsigned short* B1 = (unsigned short*)alloc((size_t)NN * 64);  // bf16 [NN][128]
    unsigned short* B2 = (unsigned short*)alloc((size_t)NN * 64);
    float* dl   = alloc(NN * 4);
    float* dr   = alloc(NN * 4);
    float* dl2  = alloc(NN * 4);
    float* dr2  = alloc(NN * 4);
    int* counts8 = (int*)alloc(8 * NN);
    int* starts8 = (int*)alloc(8 * NN);
    int* bcnt    = (int*)alloc(8 * NBKT);
    int* bstart  = (int*)alloc(8 * (NBKT + 1));
    int* bcur    = (int*)alloc(8 * NBKT);
    unsigned* recs = (unsigned*)alloc((size_t)8 * EE);
    unsigned short* sortedU = (unsigned short*)alloc((size_t)4 * EE);

    const float* WtEv = Wt;
    const float* WtEc = Wt + 8192;

    Ptr8 srcP, dstP;
    srcP.p[0] = mp_var;            dstP.p[0] = mp_var + EE;
    srcP.p[1] = mp_var + 2 * EE;   dstP.p[1] = mp_var + 3 * EE;
    srcP.p[2] = mp_cls;            dstP.p[2] = mp_cls + EE;
    srcP.p[3] = mp_cls + 2 * EE;   dstP.p[3] = mp_cls + 3 * EE;
    srcP.p[4] = adj_pos;           dstP.p[4] = adj_pos + EE;
    srcP.p[5] = adj_pos + EE;      dstP.p[5] = adj_pos;
    srcP.p[6] = adj_neg;           dstP.p[6] = adj_neg + EE;
    srcP.p[7] = adj_neg + EE;      dstP.p[7] = adj_neg;

    MArgs ma;
    ma.w[0] = sv_W;           ma.al[0] = sv_al;        ma.ar[0] = sv_ar;
    ma.w[1] = sv_W + 16384;   ma.al[1] = sv_al + 512;  ma.ar[1] = sv_ar + 512;
    ma.w[2] = sc_W;           ma.al[2] = sc_al;        ma.ar[2] = sc_ar;
    ma.w[3] = sc_W + 16384;   ma.al[3] = sc_al + 512;  ma.ar[3] = sc_ar + 512;
    ma.w[4] = cp_Wl;          ma.al[4] = cp_al;        ma.ar[4] = cp_ar;
    ma.w[5] = cp_Wr;          ma.al[5] = cp_al;        ma.ar[5] = cp_ar;
    ma.w[6] = cn_Wl;          ma.al[6] = cn_al;        ma.ar[6] = cn_ar;
    ma.w[7] = cn_Wr;          ma.al[7] = cn_al;        ma.ar[7] = cn_ar;

    // ---- two-level bucket sort of all 8 edge lists ----
    zero_bcnt<<<(8 * NBKT + 255) / 256, 256, 0, stream>>>(bcnt);
    bucket_count<<<8 * PA_B, 256, 0, stream>>>(dstP, bcnt);
    bucket_scan<<<8, 256, 0, stream>>>(bcnt, bstart, bcur);
    bucket_place<<<8 * PA_B, 256, 0, stream>>>(srcP, dstP, bcur, recs);
    bucket_final<<<8 * NBKT, 256, 0, stream>>>(recs, bstart, starts8, counts8, sortedU);

    transpose_emb<<<64, 256, 0, stream>>>(W_var_emb, W_cls_emb, Wt);
    make_M<<<8, 256, 0, stream>>>(ma, Mbuf);
    embed_ln<<<NN / 8, 128, 0, stream>>>(x_var, WtEv, ln_var_g, ln_var_b, var_pw, sv_b, F, C);
    embed_ln<<<NN / 8, 128, 0, stream>>>(x_cls, WtEc, ln_cls_g, ln_cls_b, cls_pw, sc_b, G, D);
    init_out<<<(2 * NN * 128 + 255) / 256, 256, 0, stream>>>(cp_b, cn_b, out0);

    const int PB = (NN + 63) / 64;

    // ---- self attention ----
    for (int side = 0; side < 2; ++side) {
        const float* h   = side ? D : C;
        float*       acc = side ? G : F;
        const float* pw  = side ? cls_pw : var_pw;
        for (int p = 0; p < 2; ++p) {
            int seg = side * 2 + p;
            mfma_proj<<<PB, 256, 0, stream>>>(h, ma.w[seg], Mbuf + seg * 1024,
                                              B1, (float4*)dl, (float4*)dr);
            agg_sorted<<<NN, 128, 0, stream>>>(starts8 + seg * NN, counts8 + seg * NN,
                                               sortedU + (size_t)seg * EE,
                                               dl, dr, B1, pw, p, 1, acc);
        }
    }

    // ---- cross attention ----
    for (int sign = 0; sign < 2; ++sign) {
        int pl = 4 + sign * 2;
        int pr = 5 + sign * 2;
        int segV = 4 + sign * 2;
        int segC = 5 + sign * 2;
        mfma_proj<<<PB, 256, 0, stream>>>(F, ma.w[pl], Mbuf + pl * 1024,
                                          B1, (float4*)dl, (float4*)dr);    // dl=al, dr=ar_
        mfma_proj<<<PB, 256, 0, stream>>>(G, ma.w[pr], Mbuf + pr * 1024,
                                          B2, (float4*)dl2, (float4*)dr2);  // dl2=al_, dr2=ar
        agg_sorted<<<NN, 128, 0, stream>>>(starts8 + segV * NN, counts8 + segV * NN,
                                           sortedU + (size_t)segV * EE,
                                           dl, dr2, B2, nullptr, 0, 0, out0);
        agg_sorted<<<NN, 128, 0, stream>>>(starts8 + segC * NN, counts8 + segC * NN,
                                           sortedU + (size_t)segC * EE,
                                           dl2, dr, B1, nullptr, 0, 0, out1);
    }
}